// Round 1
// baseline (3971.695 us; speedup 1.0000x reference)
//
#include <hip/hip_runtime.h>
#include <math.h>

#define LRELU_A 0.2f
#define NEGBIG (-9.0e15f)

__device__ __forceinline__ float sigm(float x){ return 1.0f/(1.0f+expf(-x)); }

// ---------------------------------------------------------------------------
// Generic GRU + time-attention pooling.
//   x: [N][T][INF] contiguous, Wih: [384][INF], Whh: [384][128]
//   out[n][j] = sum_t softmax_t(h_t . aw + ab) * h_t[j]
// Block: 256 threads handles M sequences; online softmax over t (no history).
// ---------------------------------------------------------------------------
template<int INF, int M, int T>
__global__ __launch_bounds__(256) void gru_attn_kernel(
    const float* __restrict__ x,
    const float* __restrict__ Wih,
    const float* __restrict__ Whh,
    const float* __restrict__ bih,
    const float* __restrict__ bhh,
    const float* __restrict__ aw,
    const float* __restrict__ ab,
    float* __restrict__ out)
{
    constexpr int H = 128;
    constexpr int HP = 132;           // +4 pad: bank spread, keeps 16B align
    constexpr int INFP = INF + 4;
    constexpr int PA = (M*384)/256;   // (s,k) pairs per thread
    constexpr int PB = (M*H)/256;     // (s,j) pairs per thread

    __shared__ __align__(16) float xt[M][INFP];
    __shared__ __align__(16) float hbuf[2][M][HP];
    __shared__ __align__(16) float gA[M][388];   // k<256: gi+gh ; k>=256: gi_n
    __shared__ __align__(16) float gB[M][HP];    // gh_n
    __shared__ float mst[M], lst[M], alst[M], pst[M];

    const int tid = threadIdx.x;
    const int s0 = blockIdx.x * M;

    float acc[PB];
#pragma unroll
    for (int i=0;i<PB;i++) acc[i]=0.0f;
    if (tid < M){ mst[tid] = -INFINITY; lst[tid] = 0.0f; }
    __syncthreads();

    int cur = 0;
    for (int t=0; t<T; ++t){
        // stage x_t tile
        for (int idx = tid; idx < M*INF; idx += 256){
            int s = idx / INF, f = idx % INF;
            xt[s][f] = x[(size_t)(s0+s)*(T*INF) + t*INF + f];
        }
        __syncthreads();
        // phase A: gates pre-activation. lanes 0..M-1 share k -> Whh reads broadcast
#pragma unroll 1
        for (int i=0;i<PA;i++){
            int idx = i*256 + tid;
            int s = idx & (M-1);
            int k = idx / M;
            const float* wr = Wih + (size_t)k*INF;
            float4 sg = {0.f,0.f,0.f,0.f};
#pragma unroll
            for (int f=0; f<INF; f+=4){
                float4 xv = *(const float4*)&xt[s][f];
                float4 wv = *(const float4*)&wr[f];
                sg.x += xv.x*wv.x; sg.y += xv.y*wv.y;
                sg.z += xv.z*wv.z; sg.w += xv.w*wv.w;
            }
            float gi = bih[k] + ((sg.x+sg.y)+(sg.z+sg.w));
            float gh = bhh[k];
            if (t > 0){
                const float* wh = Whh + (size_t)k*H;
                float4 sh = {0.f,0.f,0.f,0.f};
#pragma unroll
                for (int j=0;j<H;j+=4){
                    float4 hv = *(const float4*)&hbuf[cur^1][s][j];
                    float4 wv = *(const float4*)&wh[j];
                    sh.x += hv.x*wv.x; sh.y += hv.y*wv.y;
                    sh.z += hv.z*wv.z; sh.w += hv.w*wv.w;
                }
                gh += ((sh.x+sh.y)+(sh.z+sh.w));
            }
            if (k < 256) gA[s][k] = gi + gh;
            else { gA[s][k] = gi; gB[s][k-256] = gh; }
        }
        __syncthreads();
        // phase B: nonlinearity + state update
#pragma unroll
        for (int i=0;i<PB;i++){
            int idx = i*256 + tid;
            int j = idx & (H-1);
            int s = idx / H;
            float r = sigm(gA[s][j]);
            float z = sigm(gA[s][H+j]);
            float n = tanhf(gA[s][256+j] + r*gB[s][j]);
            float hp = (t>0) ? hbuf[cur^1][s][j] : 0.0f;
            hbuf[cur][s][j] = (1.0f - z)*n + z*hp;
        }
        __syncthreads();
        // phase C: per-seq attention score + online-softmax state
        if (tid < M){
            int s = tid;
            float a0=0.f,a1=0.f,a2=0.f,a3=0.f;
            for (int j=0;j<H;j+=4){
                a0 += hbuf[cur][s][j]  *aw[j];
                a1 += hbuf[cur][s][j+1]*aw[j+1];
                a2 += hbuf[cur][s][j+2]*aw[j+2];
                a3 += hbuf[cur][s][j+3]*aw[j+3];
            }
            float sc = ab[0] + ((a0+a1)+(a2+a3));
            float mo = mst[s];
            float mn = fmaxf(mo, sc);
            float al = expf(mo - mn);   // t==0: exp(-inf)=0
            float p  = expf(sc - mn);
            lst[s] = lst[s]*al + p;
            mst[s] = mn; alst[s] = al; pst[s] = p;
        }
        __syncthreads();
        // phase D: online weighted accumulation
#pragma unroll
        for (int i=0;i<PB;i++){
            int idx = i*256 + tid;
            int j = idx & (H-1);
            int s = idx / H;
            acc[i] = acc[i]*alst[s] + pst[s]*hbuf[cur][s][j];
        }
        cur ^= 1;
        __syncthreads();
    }
#pragma unroll
    for (int i=0;i<PB;i++){
        int idx = i*256 + tid;
        int j = idx & (H-1);
        int s = idx / H;
        out[(size_t)(s0+s)*H + j] = acc[i] / lst[s];
    }
}

// ---------------------------------------------------------------------------
// Wh = h @ W  (rows gathered with stride), W staged fully in LDS (64 KB)
// ---------------------------------------------------------------------------
__global__ __launch_bounds__(256) void wh_kernel(
    const float* __restrict__ hsrc, int row_stride,
    const float* __restrict__ W,
    float* __restrict__ Wh)
{
    __shared__ __align__(16) float Wl[128*128];
    __shared__ __align__(16) float ht[16][132];
    const int tid = threadIdx.x;
    const int s0 = blockIdx.x*16;
    for (int i = tid; i < 128*128/4; i += 256) ((float4*)Wl)[i] = ((const float4*)W)[i];
    for (int idx = tid; idx < 16*128; idx += 256){
        int s = idx>>7, j = idx&127;
        ht[s][j] = hsrc[(size_t)(s0+s)*row_stride + j];
    }
    __syncthreads();
#pragma unroll 1
    for (int i=0;i<8;i++){
        int idx = i*256+tid;
        int o = idx & 127, s = idx >> 7;
        float a0=0.f,a1=0.f,a2=0.f,a3=0.f;
        for (int j=0;j<128;j+=4){
            a0 += ht[s][j]  *Wl[(j  )*128+o];
            a1 += ht[s][j+1]*Wl[(j+1)*128+o];
            a2 += ht[s][j+2]*Wl[(j+2)*128+o];
            a3 += ht[s][j+3]*Wl[(j+3)*128+o];
        }
        Wh[(size_t)(s0+s)*128 + o] = (a0+a1)+(a2+a3);
    }
}

// el[i] = Wh[i].a[:128], er[i] = Wh[i].a[128:]; one wave per row
__global__ __launch_bounds__(256) void elr_kernel(
    const float* __restrict__ Wh, const float* __restrict__ a,
    float* __restrict__ el, float* __restrict__ er, int S)
{
    int wave = threadIdx.x >> 6, lane = threadIdx.x & 63;
    int i = blockIdx.x*4 + wave;
    if (i >= S) return;
    float w0 = Wh[(size_t)i*128+lane], w1 = Wh[(size_t)i*128+64+lane];
    float v1 = w0*a[lane]     + w1*a[64+lane];
    float v2 = w0*a[128+lane] + w1*a[192+lane];
    for (int off=32; off; off>>=1){ v1 += __shfl_down(v1,off); v2 += __shfl_down(v2,off); }
    if (lane==0){ el[i]=v1; er[i]=v2; }
}

// GAT attention+aggregate: one wave per row, skip non-neighbors (uniform branch)
__global__ __launch_bounds__(256) void gat_intra_att_kernel(
    const float* __restrict__ Wh, const float* __restrict__ el,
    const float* __restrict__ er, const int* __restrict__ sec,
    float* __restrict__ outp, int S)
{
    int wave = threadIdx.x>>6, lane = threadIdx.x&63;
    int i = blockIdx.x*4 + wave;
    if (i>=S) return;
    int si = sec[i];
    float eli = el[i];
    float m = NEGBIG;
    for (int jb=0; jb<S; jb+=64){
        int j = jb + lane;
        float e = NEGBIG;
        if (sec[j]==si){ float v = eli + er[j]; e = v>0.f? v : LRELU_A*v; }
        m = fmaxf(m,e);
    }
    for (int off=32; off; off>>=1) m = fmaxf(m, __shfl_xor(m, off));
    float l = 0.f, c0=0.f, c1=0.f;
    for (int j=0;j<S;j++){
        if (sec[j]!=si) continue;               // exp(NEG-m)==0 exactly
        float v = eli + er[j]; v = v>0.f? v : LRELU_A*v;
        float p = expf(v-m);
        l += p;
        c0 += p*Wh[(size_t)j*128+lane];
        c1 += p*Wh[(size_t)j*128+64+lane];
    }
    c0 /= l; c1 /= l;
    outp[(size_t)i*128+lane]    = c0>0.f? c0 : expm1f(c0);
    outp[(size_t)i*128+64+lane] = c1>0.f? c1 : expm1f(c1);
}

// lg GRU: T=1, h0=0 => gh=bhh, attention weight==1 => lg=(1-z)*n
__global__ __launch_bounds__(256) void lg_kernel(
    const float* __restrict__ xin, const float* __restrict__ Wih,
    const float* __restrict__ bih, const float* __restrict__ bhh,
    float* __restrict__ lg)
{
    __shared__ __align__(16) float xt[16][132];
    __shared__ __align__(16) float gA[16][388];
    const int tid=threadIdx.x;
    const int s0=blockIdx.x*16;
    for (int idx=tid; idx<16*128; idx+=256){ int s=idx>>7,j=idx&127; xt[s][j]=xin[(size_t)(s0+s)*128+j]; }
    __syncthreads();
#pragma unroll 1
    for (int i=0;i<24;i++){
        int idx=i*256+tid; int s=idx&15, k=idx>>4;
        const float* wr = Wih + (size_t)k*128;
        float4 sg = {0.f,0.f,0.f,0.f};
#pragma unroll
        for (int f=0;f<128;f+=4){
            float4 xv=*(const float4*)&xt[s][f]; float4 wv=*(const float4*)&wr[f];
            sg.x += xv.x*wv.x; sg.y += xv.y*wv.y;
            sg.z += xv.z*wv.z; sg.w += xv.w*wv.w;
        }
        gA[s][k]= bih[k] + ((sg.x+sg.y)+(sg.z+sg.w));
    }
    __syncthreads();
#pragma unroll
    for (int i=0;i<8;i++){
        int idx=i*256+tid; int j=idx&127, s=idx>>7;
        float r = sigm(gA[s][j]     + bhh[j]);
        float z = sigm(gA[s][128+j] + bhh[128+j]);
        float n = tanhf(gA[s][256+j] + r*bhh[256+j]);
        lg[(size_t)(s0+s)*128+j] = (1.0f-z)*n;
    }
}

// per-sector mean: 16 blocks x 128 threads
__global__ __launch_bounds__(128) void sector_mean_kernel(
    const float* __restrict__ lg, const int* __restrict__ sec,
    float* __restrict__ secf, int S)
{
    int g = blockIdx.x, j = threadIdx.x;
    float sum=0.f; int cnt=0;
    for (int s=0;s<S;s++){
        if (sec[s]==g){ sum += lg[(size_t)s*128+j]; cnt++; }
    }
    secf[g*128+j] = sum / fmaxf((float)cnt,1.0f);
}

// 16-node inter-sector GAT, one block (handles empty-row uniform case)
__global__ __launch_bounds__(256) void gat_inter_kernel(
    const float* __restrict__ secf, const int* __restrict__ adj,
    const float* __restrict__ W, const float* __restrict__ a,
    float* __restrict__ outp)
{
    __shared__ __align__(16) float hs[16][132];
    __shared__ __align__(16) float Whs[16][132];
    __shared__ float el[16], er[16];
    __shared__ float att[16][16];
    const int tid=threadIdx.x;
    for (int idx=tid; idx<2048; idx+=256){ int s=idx>>7,j=idx&127; hs[s][j]=secf[idx]; }
    __syncthreads();
#pragma unroll 1
    for (int i=0;i<8;i++){
        int idx=i*256+tid; int o=idx&127, s=idx>>7;
        float a0=0.f,a1=0.f,a2=0.f,a3=0.f;
        for (int j=0;j<128;j+=4){
            a0 += hs[s][j]  *W[(j  )*128+o];
            a1 += hs[s][j+1]*W[(j+1)*128+o];
            a2 += hs[s][j+2]*W[(j+2)*128+o];
            a3 += hs[s][j+3]*W[(j+3)*128+o];
        }
        Whs[s][o]=(a0+a1)+(a2+a3);
    }
    __syncthreads();
    if (tid<32){
        int s=tid&15; int second = tid>>4;
        const float* av = a + (second?128:0);
        float acc=0.f; for(int o=0;o<128;o++) acc += Whs[s][o]*av[o];
        if (second) er[s]=acc; else el[s]=acc;
    }
    __syncthreads();
    if (tid<16){
        int i=tid; float m=NEGBIG; float e[16];
        for(int j=0;j<16;j++){
            float v = el[i]+er[j]; v = v>0.f? v : LRELU_A*v;
            e[j] = (adj[i*16+j]>0)? v : NEGBIG;
            m = fmaxf(m,e[j]);
        }
        float l=0.f;
        for(int j=0;j<16;j++){ float p=expf(e[j]-m); att[i][j]=p; l+=p; }
        for(int j=0;j<16;j++) att[i][j] /= l;
    }
    __syncthreads();
#pragma unroll
    for (int i=0;i<8;i++){
        int idx=i*256+tid; int o=idx&127, s=idx>>7;
        float acc=0.f;
#pragma unroll
        for(int j=0;j<16;j++) acc += att[s][j]*Whs[j][o];
        outp[s*128+o] = acc>0.f? acc : expm1f(acc);
    }
}

// fused = [lg, la, sec_ps] @ fw + fb ; heads -> d_out[0:S]=returns, [S:2S]=moves
__global__ __launch_bounds__(256) void fused_kernel(
    const float* __restrict__ lg, const float* __restrict__ la,
    const float* __restrict__ secout, const int* __restrict__ sec,
    const float* __restrict__ fw, const float* __restrict__ fb,
    const float* __restrict__ rw, const float* __restrict__ rb,
    const float* __restrict__ mw, const float* __restrict__ mb,
    float* __restrict__ outp, int S)
{
    __shared__ __align__(16) float cat[16][388];
    __shared__ __align__(16) float fu[16][132];
    const int tid=threadIdx.x;
    const int s0=blockIdx.x*16;
    for (int idx=tid; idx<16*128; idx+=256){
        int s=idx>>7, j=idx&127;
        cat[s][j]     = lg[(size_t)(s0+s)*128+j];
        cat[s][128+j] = la[(size_t)(s0+s)*128+j];
        cat[s][256+j] = secout[sec[s0+s]*128+j];
    }
    __syncthreads();
#pragma unroll 1
    for (int i=0;i<8;i++){
        int idx=i*256+tid; int o=idx&127, s=idx>>7;
        float a0=0.f,a1=0.f,a2=0.f,a3=0.f;
        for (int k=0;k<384;k+=4){
            a0 += cat[s][k]  *fw[(k  )*128+o];
            a1 += cat[s][k+1]*fw[(k+1)*128+o];
            a2 += cat[s][k+2]*fw[(k+2)*128+o];
            a3 += cat[s][k+3]*fw[(k+3)*128+o];
        }
        fu[s][o]= fb[o] + (a0+a1)+(a2+a3);
    }
    __syncthreads();
    if (tid<32){
        int s=tid&15; int mov = tid>>4;
        const float* w = mov? mw : rw;
        float a0=0.f,a1=0.f,a2=0.f,a3=0.f;
        for(int o=0;o<128;o+=4){
            a0+=fu[s][o]*w[o]; a1+=fu[s][o+1]*w[o+1];
            a2+=fu[s][o+2]*w[o+2]; a3+=fu[s][o+3]*w[o+3];
        }
        float acc=(a0+a1)+(a2+a3);
        if (mov) outp[S + s0+s] = sigm(acc + mb[0]);
        else     outp[s0+s]     = acc + rb[0];
    }
}

extern "C" void kernel_launch(void* const* d_in, const int* in_sizes, int n_in,
                              void* d_out, int out_size, void* d_ws, size_t ws_size,
                              hipStream_t stream) {
    const float* sf    = (const float*)d_in[0];
    const int*   sec   = (const int*)  d_in[1];
    const int*   adj   = (const int*)  d_in[2];
    const float* g1Wih = (const float*)d_in[3];
    const float* g1Whh = (const float*)d_in[4];
    const float* g1bih = (const float*)d_in[5];
    const float* g1bhh = (const float*)d_in[6];
    const float* a1w   = (const float*)d_in[7];
    const float* a1b   = (const float*)d_in[8];
    const float* giW   = (const float*)d_in[9];
    const float* gia   = (const float*)d_in[10];
    const float* ggWih = (const float*)d_in[11];
    const float* ggbih = (const float*)d_in[13];
    const float* ggbhh = (const float*)d_in[14];
    const float* gaWih = (const float*)d_in[17];
    const float* gaWhh = (const float*)d_in[18];
    const float* gabih = (const float*)d_in[19];
    const float* gabhh = (const float*)d_in[20];
    const float* aaw   = (const float*)d_in[21];
    const float* aab   = (const float*)d_in[22];
    const float* geW   = (const float*)d_in[23];
    const float* gea   = (const float*)d_in[24];
    const float* fw    = (const float*)d_in[25];
    const float* fb    = (const float*)d_in[26];
    const float* rw    = (const float*)d_in[27];
    const float* rb    = (const float*)d_in[28];
    const float* mw    = (const float*)d_in[29];
    const float* mb    = (const float*)d_in[30];

    const int S = 2048, Wk = 32;
    float* ws = (float*)d_ws;
    float* shrt  = ws;                    // 65536*128 = 8388608
    float* Wh    = shrt + 8388608;        // 262144
    float* el    = Wh   + 262144;         // 2048
    float* er    = el   + 2048;           // 2048
    float* intra = er   + 2048;           // 262144
    float* lg    = intra+ 262144;         // 262144
    float* la    = lg   + 262144;         // 262144
    float* secf  = la   + 262144;         // 2048
    float* seco  = secf + 2048;           // 2048

    // 1. short-term GRU+attn over 65536 windows (T=5, F=16)
    gru_attn_kernel<16,16,5><<<4096,256,0,stream>>>(sf, g1Wih, g1Whh, g1bih, g1bhh, a1w, a1b, shrt);
    // 2. intra-sector GAT on last-window embeddings
    wh_kernel<<<128,256,0,stream>>>(shrt + 31*128, Wk*128, giW, Wh);
    elr_kernel<<<512,256,0,stream>>>(Wh, gia, el, er, S);
    gat_intra_att_kernel<<<512,256,0,stream>>>(Wh, el, er, sec, intra, S);
    // 3. lg GRU (T=1 simplification)
    lg_kernel<<<128,256,0,stream>>>(intra, ggWih, ggbih, ggbhh, lg);
    // 4. la GRU+attn over windows (T=32, INF=128)
    gru_attn_kernel<128,8,32><<<256,256,0,stream>>>(shrt, gaWih, gaWhh, gabih, gabhh, aaw, aab, la);
    // 5. sector means
    sector_mean_kernel<<<16,128,0,stream>>>(lg, sec, secf, S);
    // 6. inter-sector GAT (16 nodes)
    gat_inter_kernel<<<1,256,0,stream>>>(secf, adj, geW, gea, seco);
    // 7. fusion + heads
    fused_kernel<<<128,256,0,stream>>>(lg, la, seco, sec, fw, fb, rw, rb, mw, mb, (float*)d_out, S);
}

// Round 2
// 786.131 us; speedup vs baseline: 5.0522x; 5.0522x over previous
//
#include <hip/hip_runtime.h>
#include <math.h>

#define LRELU_A 0.2f
#define NEGBIG (-9.0e15f)

typedef _Float16 f16x8 __attribute__((ext_vector_type(8)));
typedef float floatx4 __attribute__((ext_vector_type(4)));

__device__ __forceinline__ float sigm(float x){ return 1.0f/(1.0f+expf(-x)); }
__device__ __forceinline__ float fsigm(float x){ return 1.0f/(1.0f+__expf(-x)); }
__device__ __forceinline__ float ftanh(float x){
    float ax = fabsf(x);
    float e = __expf(2.0f*ax);
    float t = 1.0f - 2.0f/(e + 1.0f);
    return copysignf(t, x);
}

// ---------------------------------------------------------------------------
// Build fused f16 weight matrix Wcat[512][KTOT], KTOT = INFPAD+128.
// rows 0..255:   [Wih_rz (zero-pad to INFPAD) | Whh_rz]   (r,z gates fused)
// rows 256..383: [Wih_n  (zero-pad)           | 0      ]  (gi_n)
// rows 384..511: [0                           | Whh_n  ]  (gh_n)
// ---------------------------------------------------------------------------
__global__ __launch_bounds__(256) void build_wcat_kernel(
    const float* __restrict__ Wih, const float* __restrict__ Whh,
    _Float16* __restrict__ Wcat, int INF, int INFPAD)
{
    int KTOT = INFPAD + 128;
    int total = 512*KTOT;
    for (int idx = blockIdx.x*256 + threadIdx.x; idx < total; idx += gridDim.x*256){
        int r = idx / KTOT, k = idx - r*KTOT;
        float v = 0.0f;
        if (r < 256){
            if (k < INFPAD){ if (k < INF) v = Wih[r*INF + k]; }
            else v = Whh[r*128 + (k - INFPAD)];
        } else if (r < 384){
            if (k < INF) v = Wih[r*INF + k];
        } else {
            if (k >= INFPAD) v = Whh[(r-128)*128 + (k - INFPAD)];
        }
        Wcat[idx] = (_Float16)v;
    }
}

// ---------------------------------------------------------------------------
// MFMA GRU + time-attention (online softmax). f16 MFMA, fp32 state/accum.
// LDS row per seq: [x_t (INFPAD cols, zero-padded) | h (128) | pad 8].
// Wave w handles gate-col blocks jb = w + i*NW (i<8/NW), all 4 gate types,
// MT seq-tiles. C-layout: col=lane&15 (gate col), row=quad*4+reg (seq).
// ---------------------------------------------------------------------------
template<int INF, int INFPAD, int T, int MT, int NW>
__global__ __launch_bounds__(NW*64) void gru_attn_mfma(
    const float* __restrict__ x,
    const _Float16* __restrict__ Wcat,
    const float* __restrict__ bih, const float* __restrict__ bhh,
    const float* __restrict__ aw, const float* __restrict__ ab,
    float* __restrict__ out)
{
    constexpr int KTOT = INFPAD + 128;
    constexpr int KB   = KTOT/32;
    constexpr int XKB  = INFPAD/32;   // K-blocks covering the x part
    constexpr int RS   = KTOT + 8;    // +8 f16 pad: 2-way-max bank aliasing
    constexpr int M    = MT*16;
    constexpr int JBW  = 8/NW;

    const int tid  = threadIdx.x;
    const int w    = tid >> 6, lane = tid & 63;
    const int c    = lane & 15, quad = lane >> 4;
    const long s0  = (long)blockIdx.x * M;

    __shared__ __align__(16) _Float16 cat[M][RS];
    __shared__ float scpart[NW][M];
    __shared__ float mst[M], lst[M], alst[M], pst[M];

    for (int idx = tid; idx < M*RS; idx += NW*64) ((_Float16*)cat)[idx] = (_Float16)0.0f;
    if (tid < M){ mst[tid] = -INFINITY; lst[tid] = 0.0f; }

    int jbs[JBW];
    float brzr[JBW], brzz[JBW], bnn_[JBW], bhn_[JBW], awr[JBW];
    const _Float16* bp[JBW][4];
#pragma unroll
    for (int i=0;i<JBW;i++){
        int jb = w + i*NW; jbs[i] = jb;
        int j = jb*16 + c;
        brzr[i] = bih[j]       + bhh[j];
        brzz[i] = bih[128 + j] + bhh[128 + j];
        bnn_[i] = bih[256 + j];
        bhn_[i] = bhh[256 + j];
        awr[i]  = aw[j];
        bp[i][0] = Wcat + (size_t)(      j)*KTOT + quad*8;
        bp[i][1] = Wcat + (size_t)(128 + j)*KTOT + quad*8;
        bp[i][2] = Wcat + (size_t)(256 + j)*KTOT + quad*8;
        bp[i][3] = Wcat + (size_t)(384 + j)*KTOT + quad*8;
    }

    float hreg[JBW][MT][4], aacc[JBW][MT][4];
#pragma unroll
    for (int i=0;i<JBW;i++)
#pragma unroll
        for (int mt=0;mt<MT;mt++)
#pragma unroll
            for (int r4=0;r4<4;r4++){ hreg[i][mt][r4]=0.0f; aacc[i][mt][r4]=0.0f; }

    // stage x_0
    for (int idx = tid; idx < M*INF; idx += NW*64){
        int s = idx / INF, f = idx - (idx/INF)*INF;
        cat[s][f] = (_Float16)x[(size_t)(s0+s)*(T*INF) + f];
    }
    __syncthreads();

#pragma unroll 1
    for (int t=0; t<T; ++t){
        // A-fragments for all seq-tiles / K-blocks (LDS)
        f16x8 af[MT][KB];
#pragma unroll
        for (int mt=0;mt<MT;mt++)
#pragma unroll
            for (int kb=0;kb<KB;kb++)
                af[mt][kb] = *(const f16x8*)&cat[mt*16 + c][kb*32 + quad*8];

        floatx4 acc[JBW][4][MT];
#pragma unroll
        for (int i=0;i<JBW;i++)
#pragma unroll
            for (int ty=0;ty<4;ty++)
#pragma unroll
                for (int mt=0;mt<MT;mt++)
                    acc[i][ty][mt] = (floatx4){0.0f,0.0f,0.0f,0.0f};

#pragma unroll
        for (int i=0;i<JBW;i++){
#pragma unroll
            for (int ty=0;ty<4;ty++){
                const int k0 = (ty==3) ? XKB : 0;     // gh_n rows: h part only
                const int k1 = (ty==2) ? XKB : KB;    // gi_n rows: x part only
#pragma unroll
                for (int kb=k0; kb<k1; kb++){
                    f16x8 b = *(const f16x8*)(bp[i][ty] + kb*32);
#pragma unroll
                    for (int mt=0;mt<MT;mt++)
                        acc[i][ty][mt] = __builtin_amdgcn_mfma_f32_16x16x32_f16(
                            af[mt][kb], b, acc[i][ty][mt], 0, 0, 0);
                }
            }
        }
        __syncthreads();   // all A-frag reads of step t done

        // epilogue: gates + h update, in C-layout registers
#pragma unroll
        for (int i=0;i<JBW;i++)
#pragma unroll
        for (int mt=0;mt<MT;mt++)
#pragma unroll
        for (int reg=0;reg<4;reg++){
            float r = fsigm(acc[i][0][mt][reg] + brzr[i]);
            float z = fsigm(acc[i][1][mt][reg] + brzz[i]);
            float n = ftanh(acc[i][2][mt][reg] + bnn_[i] + r*(acc[i][3][mt][reg] + bhn_[i]));
            float h2 = (1.0f - z)*n + z*hreg[i][mt][reg];
            hreg[i][mt][reg] = h2;
            cat[mt*16 + quad*4 + reg][INFPAD + jbs[i]*16 + c] = (_Float16)h2;
        }

        // attention partial scores: reduce over gate cols (c lanes + jb in-lane)
#pragma unroll
        for (int mt=0;mt<MT;mt++){
            float p[4];
#pragma unroll
            for (int reg=0;reg<4;reg++){
                p[reg] = 0.0f;
#pragma unroll
                for (int i=0;i<JBW;i++) p[reg] += hreg[i][mt][reg]*awr[i];
#pragma unroll
                for (int off=1; off<16; off<<=1) p[reg] += __shfl_xor(p[reg], off);
            }
            if (c == 0){
#pragma unroll
                for (int reg=0;reg<4;reg++) scpart[w][mt*16 + quad*4 + reg] = p[reg];
            }
        }

        // stage x_{t+1} (overlapped; x region disjoint from h region)
        if (t+1 < T){
            for (int idx = tid; idx < M*INF; idx += NW*64){
                int s = idx / INF, f = idx - (idx/INF)*INF;
                cat[s][f] = (_Float16)x[(size_t)(s0+s)*(T*INF) + (size_t)(t+1)*INF + f];
            }
        }
        __syncthreads();

        // online softmax state (one thread per seq)
        if (tid < M){
            int s = tid;
            float sc = ab[0];
#pragma unroll
            for (int ww=0; ww<NW; ww++) sc += scpart[ww][s];
            float mo = mst[s], mn = fmaxf(mo, sc);
            float al = __expf(mo - mn), pp = __expf(sc - mn);
            lst[s] = lst[s]*al + pp; mst[s] = mn; alst[s] = al; pst[s] = pp;
        }
        __syncthreads();

        // online weighted accumulation (alst/pst broadcast reads)
#pragma unroll
        for (int i=0;i<JBW;i++)
#pragma unroll
        for (int mt=0;mt<MT;mt++)
#pragma unroll
        for (int reg=0;reg<4;reg++){
            int s = mt*16 + quad*4 + reg;
            aacc[i][mt][reg] = aacc[i][mt][reg]*alst[s] + pst[s]*hreg[i][mt][reg];
        }
    }

#pragma unroll
    for (int i=0;i<JBW;i++)
#pragma unroll
    for (int mt=0;mt<MT;mt++)
#pragma unroll
    for (int reg=0;reg<4;reg++){
        int s = mt*16 + quad*4 + reg;
        out[(size_t)(s0+s)*128 + jbs[i]*16 + c] = aacc[i][mt][reg] / lst[s];
    }
}

// ---------------------------------------------------------------------------
// Wh = h @ W  (rows gathered with stride), W staged fully in LDS (64 KB)
// ---------------------------------------------------------------------------
__global__ __launch_bounds__(256) void wh_kernel(
    const float* __restrict__ hsrc, int row_stride,
    const float* __restrict__ W,
    float* __restrict__ Wh)
{
    __shared__ __align__(16) float Wl[128*128];
    __shared__ __align__(16) float ht[16][132];
    const int tid = threadIdx.x;
    const int s0 = blockIdx.x*16;
    for (int i = tid; i < 128*128/4; i += 256) ((float4*)Wl)[i] = ((const float4*)W)[i];
    for (int idx = tid; idx < 16*128; idx += 256){
        int s = idx>>7, j = idx&127;
        ht[s][j] = hsrc[(size_t)(s0+s)*row_stride + j];
    }
    __syncthreads();
#pragma unroll 1
    for (int i=0;i<8;i++){
        int idx = i*256+tid;
        int o = idx & 127, s = idx >> 7;
        float a0=0.f,a1=0.f,a2=0.f,a3=0.f;
        for (int j=0;j<128;j+=4){
            a0 += ht[s][j]  *Wl[(j  )*128+o];
            a1 += ht[s][j+1]*Wl[(j+1)*128+o];
            a2 += ht[s][j+2]*Wl[(j+2)*128+o];
            a3 += ht[s][j+3]*Wl[(j+3)*128+o];
        }
        Wh[(size_t)(s0+s)*128 + o] = (a0+a1)+(a2+a3);
    }
}

__global__ __launch_bounds__(256) void elr_kernel(
    const float* __restrict__ Wh, const float* __restrict__ a,
    float* __restrict__ el, float* __restrict__ er, int S)
{
    int wave = threadIdx.x >> 6, lane = threadIdx.x & 63;
    int i = blockIdx.x*4 + wave;
    if (i >= S) return;
    float w0 = Wh[(size_t)i*128+lane], w1 = Wh[(size_t)i*128+64+lane];
    float v1 = w0*a[lane]     + w1*a[64+lane];
    float v2 = w0*a[128+lane] + w1*a[192+lane];
    for (int off=32; off; off>>=1){ v1 += __shfl_down(v1,off); v2 += __shfl_down(v2,off); }
    if (lane==0){ el[i]=v1; er[i]=v2; }
}

__global__ __launch_bounds__(256) void gat_intra_att_kernel(
    const float* __restrict__ Wh, const float* __restrict__ el,
    const float* __restrict__ er, const int* __restrict__ sec,
    float* __restrict__ outp, int S)
{
    int wave = threadIdx.x>>6, lane = threadIdx.x&63;
    int i = blockIdx.x*4 + wave;
    if (i>=S) return;
    int si = sec[i];
    float eli = el[i];
    float m = NEGBIG;
    for (int jb=0; jb<S; jb+=64){
        int j = jb + lane;
        float e = NEGBIG;
        if (sec[j]==si){ float v = eli + er[j]; e = v>0.f? v : LRELU_A*v; }
        m = fmaxf(m,e);
    }
    for (int off=32; off; off>>=1) m = fmaxf(m, __shfl_xor(m, off));
    float l = 0.f, c0=0.f, c1=0.f;
    for (int j=0;j<S;j++){
        if (sec[j]!=si) continue;
        float v = eli + er[j]; v = v>0.f? v : LRELU_A*v;
        float p = expf(v-m);
        l += p;
        c0 += p*Wh[(size_t)j*128+lane];
        c1 += p*Wh[(size_t)j*128+64+lane];
    }
    c0 /= l; c1 /= l;
    outp[(size_t)i*128+lane]    = c0>0.f? c0 : expm1f(c0);
    outp[(size_t)i*128+64+lane] = c1>0.f? c1 : expm1f(c1);
}

// lg GRU: T=1, h0=0 => gh=bhh, attention weight==1 => lg=(1-z)*n
__global__ __launch_bounds__(256) void lg_kernel(
    const float* __restrict__ xin, const float* __restrict__ Wih,
    const float* __restrict__ bih, const float* __restrict__ bhh,
    float* __restrict__ lg)
{
    __shared__ __align__(16) float xt[16][132];
    __shared__ __align__(16) float gA[16][388];
    const int tid=threadIdx.x;
    const int s0=blockIdx.x*16;
    for (int idx=tid; idx<16*128; idx+=256){ int s=idx>>7,j=idx&127; xt[s][j]=xin[(size_t)(s0+s)*128+j]; }
    __syncthreads();
#pragma unroll 1
    for (int i=0;i<24;i++){
        int idx=i*256+tid; int s=idx&15, k=idx>>4;
        const float* wr = Wih + (size_t)k*128;
        float4 sg = {0.f,0.f,0.f,0.f};
#pragma unroll
        for (int f=0;f<128;f+=4){
            float4 xv=*(const float4*)&xt[s][f]; float4 wv=*(const float4*)&wr[f];
            sg.x += xv.x*wv.x; sg.y += xv.y*wv.y;
            sg.z += xv.z*wv.z; sg.w += xv.w*wv.w;
        }
        gA[s][k]= bih[k] + ((sg.x+sg.y)+(sg.z+sg.w));
    }
    __syncthreads();
#pragma unroll
    for (int i=0;i<8;i++){
        int idx=i*256+tid; int j=idx&127, s=idx>>7;
        float r = sigm(gA[s][j]     + bhh[j]);
        float z = sigm(gA[s][128+j] + bhh[128+j]);
        float n = tanhf(gA[s][256+j] + r*bhh[256+j]);
        lg[(size_t)(s0+s)*128+j] = (1.0f-z)*n;
    }
}

__global__ __launch_bounds__(128) void sector_mean_kernel(
    const float* __restrict__ lg, const int* __restrict__ sec,
    float* __restrict__ secf, int S)
{
    int g = blockIdx.x, j = threadIdx.x;
    float sum=0.f; int cnt=0;
    for (int s=0;s<S;s++){
        if (sec[s]==g){ sum += lg[(size_t)s*128+j]; cnt++; }
    }
    secf[g*128+j] = sum / fmaxf((float)cnt,1.0f);
}

__global__ __launch_bounds__(256) void gat_inter_kernel(
    const float* __restrict__ secf, const int* __restrict__ adj,
    const float* __restrict__ W, const float* __restrict__ a,
    float* __restrict__ outp)
{
    __shared__ __align__(16) float hs[16][132];
    __shared__ __align__(16) float Whs[16][132];
    __shared__ float el[16], er[16];
    __shared__ float att[16][16];
    const int tid=threadIdx.x;
    for (int idx=tid; idx<2048; idx+=256){ int s=idx>>7,j=idx&127; hs[s][j]=secf[idx]; }
    __syncthreads();
#pragma unroll 1
    for (int i=0;i<8;i++){
        int idx=i*256+tid; int o=idx&127, s=idx>>7;
        float a0=0.f,a1=0.f,a2=0.f,a3=0.f;
        for (int j=0;j<128;j+=4){
            a0 += hs[s][j]  *W[(j  )*128+o];
            a1 += hs[s][j+1]*W[(j+1)*128+o];
            a2 += hs[s][j+2]*W[(j+2)*128+o];
            a3 += hs[s][j+3]*W[(j+3)*128+o];
        }
        Whs[s][o]=(a0+a1)+(a2+a3);
    }
    __syncthreads();
    if (tid<32){
        int s=tid&15; int second = tid>>4;
        const float* av = a + (second?128:0);
        float acc=0.f; for(int o=0;o<128;o++) acc += Whs[s][o]*av[o];
        if (second) er[s]=acc; else el[s]=acc;
    }
    __syncthreads();
    if (tid<16){
        int i=tid; float m=NEGBIG; float e[16];
        for(int j=0;j<16;j++){
            float v = el[i]+er[j]; v = v>0.f? v : LRELU_A*v;
            e[j] = (adj[i*16+j]>0)? v : NEGBIG;
            m = fmaxf(m,e[j]);
        }
        float l=0.f;
        for(int j=0;j<16;j++){ float p=expf(e[j]-m); att[i][j]=p; l+=p; }
        for(int j=0;j<16;j++) att[i][j] /= l;
    }
    __syncthreads();
#pragma unroll
    for (int i=0;i<8;i++){
        int idx=i*256+tid; int o=idx&127, s=idx>>7;
        float acc=0.f;
#pragma unroll
        for(int j=0;j<16;j++) acc += att[s][j]*Whs[j][o];
        outp[s*128+o] = acc>0.f? acc : expm1f(acc);
    }
}

__global__ __launch_bounds__(256) void fused_kernel(
    const float* __restrict__ lg, const float* __restrict__ la,
    const float* __restrict__ secout, const int* __restrict__ sec,
    const float* __restrict__ fw, const float* __restrict__ fb,
    const float* __restrict__ rw, const float* __restrict__ rb,
    const float* __restrict__ mw, const float* __restrict__ mb,
    float* __restrict__ outp, int S)
{
    __shared__ __align__(16) float cat[16][388];
    __shared__ __align__(16) float fu[16][132];
    const int tid=threadIdx.x;
    const int s0=blockIdx.x*16;
    for (int idx=tid; idx<16*128; idx+=256){
        int s=idx>>7, j=idx&127;
        cat[s][j]     = lg[(size_t)(s0+s)*128+j];
        cat[s][128+j] = la[(size_t)(s0+s)*128+j];
        cat[s][256+j] = secout[sec[s0+s]*128+j];
    }
    __syncthreads();
#pragma unroll 1
    for (int i=0;i<8;i++){
        int idx=i*256+tid; int o=idx&127, s=idx>>7;
        float a0=0.f,a1=0.f,a2=0.f,a3=0.f;
        for (int k=0;k<384;k+=4){
            a0 += cat[s][k]  *fw[(k  )*128+o];
            a1 += cat[s][k+1]*fw[(k+1)*128+o];
            a2 += cat[s][k+2]*fw[(k+2)*128+o];
            a3 += cat[s][k+3]*fw[(k+3)*128+o];
        }
        fu[s][o]= fb[o] + (a0+a1)+(a2+a3);
    }
    __syncthreads();
    if (tid<32){
        int s=tid&15; int mov = tid>>4;
        const float* w = mov? mw : rw;
        float a0=0.f,a1=0.f,a2=0.f,a3=0.f;
        for(int o=0;o<128;o+=4){
            a0+=fu[s][o]*w[o]; a1+=fu[s][o+1]*w[o+1];
            a2+=fu[s][o+2]*w[o+2]; a3+=fu[s][o+3]*w[o+3];
        }
        float acc=(a0+a1)+(a2+a3);
        if (mov) outp[S + s0+s] = sigm(acc + mb[0]);
        else     outp[s0+s]     = acc + rb[0];
    }
}

extern "C" void kernel_launch(void* const* d_in, const int* in_sizes, int n_in,
                              void* d_out, int out_size, void* d_ws, size_t ws_size,
                              hipStream_t stream) {
    const float* sf    = (const float*)d_in[0];
    const int*   sec   = (const int*)  d_in[1];
    const int*   adj   = (const int*)  d_in[2];
    const float* g1Wih = (const float*)d_in[3];
    const float* g1Whh = (const float*)d_in[4];
    const float* g1bih = (const float*)d_in[5];
    const float* g1bhh = (const float*)d_in[6];
    const float* a1w   = (const float*)d_in[7];
    const float* a1b   = (const float*)d_in[8];
    const float* giW   = (const float*)d_in[9];
    const float* gia   = (const float*)d_in[10];
    const float* ggWih = (const float*)d_in[11];
    const float* ggbih = (const float*)d_in[13];
    const float* ggbhh = (const float*)d_in[14];
    const float* gaWih = (const float*)d_in[17];
    const float* gaWhh = (const float*)d_in[18];
    const float* gabih = (const float*)d_in[19];
    const float* gabhh = (const float*)d_in[20];
    const float* aaw   = (const float*)d_in[21];
    const float* aab   = (const float*)d_in[22];
    const float* geW   = (const float*)d_in[23];
    const float* gea   = (const float*)d_in[24];
    const float* fw    = (const float*)d_in[25];
    const float* fb    = (const float*)d_in[26];
    const float* rw    = (const float*)d_in[27];
    const float* rb    = (const float*)d_in[28];
    const float* mw    = (const float*)d_in[29];
    const float* mb    = (const float*)d_in[30];

    const int S = 2048, Wk = 32;
    float* ws = (float*)d_ws;
    float* shrt  = ws;                    // 65536*128
    float* Wh    = shrt + 8388608;        // 262144
    float* el    = Wh   + 262144;         // 2048
    float* er    = el   + 2048;           // 2048
    float* intra = er   + 2048;           // 262144
    float* lg    = intra+ 262144;         // 262144
    float* la    = lg   + 262144;         // 262144
    float* secf  = la   + 262144;         // 2048
    float* seco  = secf + 2048;           // 2048
    _Float16* Wcat1 = (_Float16*)(seco + 2048);   // 512*160 f16
    _Float16* WcatA = Wcat1 + 512*160;            // 512*256 f16

    // 0. build fused f16 weights
    build_wcat_kernel<<<320,256,0,stream>>>(g1Wih, g1Whh, Wcat1, 16, 32);
    build_wcat_kernel<<<512,256,0,stream>>>(gaWih, gaWhh, WcatA, 128, 128);

    // 1. short-term GRU+attn over 65536 windows (T=5, F=16) -- MFMA
    gru_attn_mfma<16,32,5,2,4><<<2048,256,0,stream>>>(sf, Wcat1, g1bih, g1bhh, a1w, a1b, shrt);
    // 2. intra-sector GAT on last-window embeddings
    wh_kernel<<<128,256,0,stream>>>(shrt + 31*128, Wk*128, giW, Wh);
    elr_kernel<<<512,256,0,stream>>>(Wh, gia, el, er, S);
    gat_intra_att_kernel<<<512,256,0,stream>>>(Wh, el, er, sec, intra, S);
    // 3. lg GRU (T=1 simplification)
    lg_kernel<<<128,256,0,stream>>>(intra, ggWih, ggbih, ggbhh, lg);
    // 4. la GRU+attn over windows (T=32, INF=128) -- MFMA
    gru_attn_mfma<128,128,32,1,8><<<128,512,0,stream>>>(shrt, WcatA, gabih, gabhh, aaw, aab, la);
    // 5. sector means
    sector_mean_kernel<<<16,128,0,stream>>>(lg, sec, secf, S);
    // 6. inter-sector GAT (16 nodes)
    gat_inter_kernel<<<1,256,0,stream>>>(secf, adj, geW, gea, seco);
    // 7. fusion + heads
    fused_kernel<<<128,256,0,stream>>>(lg, la, seco, sec, fw, fb, rw, rb, mw, mb, (float*)d_out, S);
}

// Round 3
// 621.811 us; speedup vs baseline: 6.3873x; 1.2643x over previous
//
#include <hip/hip_runtime.h>
#include <math.h>

#define LRELU_A 0.2f
#define NEGBIG (-9.0e15f)

typedef _Float16 f16;
typedef _Float16 f16x8 __attribute__((ext_vector_type(8)));
typedef _Float16 f16x4 __attribute__((ext_vector_type(4)));
typedef float floatx4 __attribute__((ext_vector_type(4)));

__device__ __forceinline__ float sigm(float x){ return 1.0f/(1.0f+expf(-x)); }
__device__ __forceinline__ float fsigm(float x){ return 1.0f/(1.0f+__expf(-x)); }
__device__ __forceinline__ float ftanh(float x){
    float ax = fabsf(x);
    float e = __expf(2.0f*ax);
    float t = 1.0f - 2.0f/(e+1.0f);
    return copysignf(t,x);
}
__device__ __forceinline__ f16x8 load_cvt8(const float* __restrict__ p){
    float4 a = *(const float4*)p; float4 b = *(const float4*)(p+4);
    f16x8 r; r[0]=(f16)a.x; r[1]=(f16)a.y; r[2]=(f16)a.z; r[3]=(f16)a.w;
    r[4]=(f16)b.x; r[5]=(f16)b.y; r[6]=(f16)b.z; r[7]=(f16)b.w;
    return r;
}
#define MFMA16(A,B,C) __builtin_amdgcn_mfma_f32_16x16x32_f16((A),(B),(C),0,0,0)

// ---------------------------------------------------------------------------
// Wcat[512][KTOT], KTOT = INFPAD+128. rows 0..255: [Wih_rz | Whh_rz];
// 256..383: [Wih_n | 0]; 384..511: [0 | Whh_n]
// ---------------------------------------------------------------------------
__global__ __launch_bounds__(256) void build_wcat_kernel(
    const float* __restrict__ Wih, const float* __restrict__ Whh,
    f16* __restrict__ Wcat, int INF, int INFPAD)
{
    int KTOT = INFPAD + 128;
    int total = 512*KTOT;
    for (int idx = blockIdx.x*256 + threadIdx.x; idx < total; idx += gridDim.x*256){
        int r = idx / KTOT, k = idx - r*KTOT;
        float v = 0.0f;
        if (r < 256){
            if (k < INFPAD){ if (k < INF) v = Wih[r*INF + k]; }
            else v = Whh[r*128 + (k - INFPAD)];
        } else if (r < 384){
            if (k < INF) v = Wih[r*INF + k];
        } else {
            if (k >= INFPAD) v = Whh[(r-128)*128 + (k - INFPAD)];
        }
        Wcat[idx] = (f16)v;
    }
}

// out[c*R + r] = (f16) in[r*C + c]
__global__ __launch_bounds__(256) void transpose_cvt(
    const float* __restrict__ in, f16* __restrict__ out, int R, int C)
{
    for (int idx = blockIdx.x*256+threadIdx.x; idx < R*C; idx += gridDim.x*256){
        int r = idx / C, c = idx - r*C;
        out[(size_t)c*R + r] = (f16)in[idx];
    }
}

// ---------------------------------------------------------------------------
// Short GRU+attn, gate-partitioned. M=32 seqs/block, 8 waves, T=5.
// Wave w owns gate rows [w*16,w*16+16) of each of r/z/gin/ghn: A-frags in regs.
// h as MFMA-B operand from LDS (parity dbuf). 1 barrier per step.
// ---------------------------------------------------------------------------
__global__ __launch_bounds__(512,2) void gru_short(
    const float* __restrict__ x, const f16* __restrict__ Wcat,
    const float* __restrict__ bih, const float* __restrict__ bhh,
    const float* __restrict__ aw, const float* __restrict__ ab,
    f16* __restrict__ out)
{
    __shared__ __align__(16) f16 xs[5][32][40];     // [t][seq][32 cols, 16..31 zero]
    __shared__ __align__(16) f16 hs[2][32][136];    // parity dbuf
    __shared__ float scpart[2][8][32];
    const int tid = threadIdx.x, w = tid>>6, lane = tid&63;
    const int c = lane&15, quad = lane>>4;
    const int s0 = blockIdx.x*32;

    { f16x4 z4 = {0,0,0,0};
      f16x4* zx = (f16x4*)&xs[0][0][0];
      for (int i=tid; i<1600; i+=512) zx[i] = z4;
      f16x4* zh = (f16x4*)&hs[1][0][0];
      for (int i=tid; i<1088; i+=512) zh[i] = z4; }
    // stage all x (5 t): 32 seqs x 20 float4
    for (int i=tid; i<640; i+=512){
        int s = i/20, q = i - 20*s;
        float4 v = *(const float4*)&x[(size_t)(s0+s)*80 + q*4];
        int t = (q*4)>>4, f = (q*4)&15;
        f16x4 h4; h4[0]=(f16)v.x; h4[1]=(f16)v.y; h4[2]=(f16)v.z; h4[3]=(f16)v.w;
        *(f16x4*)&xs[t][s][f] = h4;
    }
    // A-fragments (weights), loop-invariant
    const int jrow = w*16 + c;
    f16x8 Ar[5], Az[5], Agi, Agh[4];
#pragma unroll
    for (int kb=0;kb<5;kb++){
        Ar[kb] = *(const f16x8*)&Wcat[(size_t)(jrow)*160 + kb*32 + quad*8];
        Az[kb] = *(const f16x8*)&Wcat[(size_t)(128+jrow)*160 + kb*32 + quad*8];
    }
    Agi = *(const f16x8*)&Wcat[(size_t)(256+jrow)*160 + quad*8];
#pragma unroll
    for (int i=0;i<4;i++)
        Agh[i] = *(const f16x8*)&Wcat[(size_t)(384+jrow)*160 + 32 + i*32 + quad*8];

    float brz_r[4], brz_z[4], b_in[4], b_hn[4], awr[4];
#pragma unroll
    for (int r=0;r<4;r++){
        int j = w*16 + quad*4 + r;
        brz_r[r] = bih[j] + bhh[j];
        brz_z[r] = bih[128+j] + bhh[128+j];
        b_in[r] = bih[256+j]; b_hn[r] = bhh[256+j];
        awr[r] = aw[j];
    }
    const float abv = ab[0];
    float hreg[2][4], aacc[2][4], m_[2], l_[2];
#pragma unroll
    for (int st=0; st<2; st++){
        m_[st] = -INFINITY; l_[st] = 0.0f;
#pragma unroll
        for (int r=0;r<4;r++){ hreg[st][r]=0.0f; aacc[st][r]=0.0f; }
    }
    __syncthreads();

#pragma unroll 1
    for (int t=0; t<5; ++t){
        const int rp = (t&1)^1, wp = t&1;
        f16x8 Bx[2], Bh[2][4];
#pragma unroll
        for (int st=0; st<2; st++){
            Bx[st] = *(const f16x8*)&xs[t][st*16+c][quad*8];
#pragma unroll
            for (int i=0;i<4;i++)
                Bh[st][i] = *(const f16x8*)&hs[rp][st*16+c][i*32+quad*8];
        }
        float sp[2];
#pragma unroll
        for (int st=0; st<2; st++){
            floatx4 ar = {0,0,0,0}, az = {0,0,0,0}, agi = {0,0,0,0}, agh = {0,0,0,0};
            ar = MFMA16(Ar[0], Bx[st], ar);
            az = MFMA16(Az[0], Bx[st], az);
            agi = MFMA16(Agi, Bx[st], agi);
#pragma unroll
            for (int i=0;i<4;i++){
                ar = MFMA16(Ar[1+i], Bh[st][i], ar);
                az = MFMA16(Az[1+i], Bh[st][i], az);
                agh = MFMA16(Agh[i], Bh[st][i], agh);
            }
            sp[st] = 0.0f;
#pragma unroll
            for (int r=0;r<4;r++){
                float rg = fsigm(ar[r] + brz_r[r]);
                float zg = fsigm(az[r] + brz_z[r]);
                float ng = ftanh(agi[r] + b_in[r] + rg*(agh[r] + b_hn[r]));
                float hn = (1.0f - zg)*ng + zg*hreg[st][r];
                hreg[st][r] = hn;
                hs[wp][st*16 + c][w*16 + quad*4 + r] = (f16)hn;
                sp[st] += hn * awr[r];
            }
        }
#pragma unroll
        for (int st=0; st<2; st++){
            sp[st] += __shfl_xor(sp[st], 16);
            sp[st] += __shfl_xor(sp[st], 32);
        }
        if (lane < 16){ scpart[wp][w][lane] = sp[0]; scpart[wp][w][16+lane] = sp[1]; }
        __syncthreads();
#pragma unroll
        for (int st=0; st<2; st++){
            float sc = abv;
#pragma unroll
            for (int ww=0; ww<8; ww++) sc += scpart[wp][ww][st*16+c];
            float mo = m_[st], mn = fmaxf(mo, sc);
            float al = __expf(mo - mn), pp = __expf(sc - mn);
            l_[st] = l_[st]*al + pp; m_[st] = mn;
#pragma unroll
            for (int r=0;r<4;r++) aacc[st][r] = aacc[st][r]*al + pp*hreg[st][r];
        }
    }
    // out (f16) via LDS transpose; final h-write parity was hs[0] -> reuse hs[0]
#pragma unroll
    for (int st=0; st<2; st++){
        float inv = 1.0f / l_[st];
#pragma unroll
        for (int r=0;r<4;r++)
            hs[0][st*16 + c][w*16 + quad*4 + r] = (f16)(aacc[st][r]*inv);
    }
    __syncthreads();
    { int s = tid>>4, p = tid&15;
      *(f16x8*)&out[(size_t)(s0+s)*128 + p*8] = *(const f16x8*)&hs[0][s][p*8]; }
}

// ---------------------------------------------------------------------------
// la GRU+attn, gate-partitioned. M=16 seqs/block, 8 waves, T=32, K=128x|128h.
// ---------------------------------------------------------------------------
__global__ __launch_bounds__(512,2) void gru_la(
    const f16* __restrict__ xseq,  // shrt16 [65536][128]
    const f16* __restrict__ Wcat,  // [512][256]
    const float* __restrict__ bih, const float* __restrict__ bhh,
    const float* __restrict__ aw, const float* __restrict__ ab,
    f16* __restrict__ out)
{
    __shared__ __align__(16) f16 xs[2][16][136];
    __shared__ __align__(16) f16 hs[2][16][136];
    __shared__ float scpart[2][8][16];
    const int tid = threadIdx.x, w = tid>>6, lane = tid&63;
    const int c = lane&15, quad = lane>>4;
    const int s0 = blockIdx.x*16;

    { f16x4 z4 = {0,0,0,0};
      f16x4* zh = (f16x4*)&hs[1][0][0];
      for (int i=tid; i<544; i+=512) zh[i] = z4; }
    if (tid < 256){
        int s = tid>>4, p = tid&15;
        *(f16x8*)&xs[0][s][p*8] = *(const f16x8*)&xseq[((size_t)(s0+s)*32 + 0)*128 + p*8];
    }
    const int jrow = w*16 + c;
    f16x8 Ar[8], Az[8], Agi[4], Agh[4];
#pragma unroll
    for (int kb=0;kb<8;kb++){
        Ar[kb] = *(const f16x8*)&Wcat[(size_t)(jrow)*256 + kb*32 + quad*8];
        Az[kb] = *(const f16x8*)&Wcat[(size_t)(128+jrow)*256 + kb*32 + quad*8];
    }
#pragma unroll
    for (int i=0;i<4;i++){
        Agi[i] = *(const f16x8*)&Wcat[(size_t)(256+jrow)*256 + i*32 + quad*8];
        Agh[i] = *(const f16x8*)&Wcat[(size_t)(384+jrow)*256 + 128 + i*32 + quad*8];
    }
    float brz_r[4], brz_z[4], b_in[4], b_hn[4], awr[4];
#pragma unroll
    for (int r=0;r<4;r++){
        int j = w*16 + quad*4 + r;
        brz_r[r] = bih[j] + bhh[j];
        brz_z[r] = bih[128+j] + bhh[128+j];
        b_in[r] = bih[256+j]; b_hn[r] = bhh[256+j];
        awr[r] = aw[j];
    }
    const float abv = ab[0];
    float hreg[4] = {0,0,0,0}, aacc[4] = {0,0,0,0};
    float m_ = -INFINITY, l_ = 0.0f;
    __syncthreads();

#pragma unroll 1
    for (int t=0; t<32; ++t){
        const int rp = (t&1)^1, wp = t&1, xp = t&1;
        f16x8 Bx[4], Bh[4];
#pragma unroll
        for (int i=0;i<4;i++){
            Bx[i] = *(const f16x8*)&xs[xp][c][i*32+quad*8];
            Bh[i] = *(const f16x8*)&hs[rp][c][i*32+quad*8];
        }
        // prefetch next x slice
        f16x8 xstage;
        const bool do_stage = (t < 31) && (tid < 256);
        if (do_stage){
            int s = tid>>4, p = tid&15;
            xstage = *(const f16x8*)&xseq[((size_t)(s0+s)*32 + t+1)*128 + p*8];
        }
        floatx4 ar = {0,0,0,0}, az = {0,0,0,0}, agi = {0,0,0,0}, agh = {0,0,0,0};
#pragma unroll
        for (int i=0;i<4;i++){
            ar = MFMA16(Ar[i], Bx[i], ar);
            az = MFMA16(Az[i], Bx[i], az);
            agi = MFMA16(Agi[i], Bx[i], agi);
        }
#pragma unroll
        for (int i=0;i<4;i++){
            ar = MFMA16(Ar[4+i], Bh[i], ar);
            az = MFMA16(Az[4+i], Bh[i], az);
            agh = MFMA16(Agh[i], Bh[i], agh);
        }
        float sp = 0.0f;
#pragma unroll
        for (int r=0;r<4;r++){
            float rg = fsigm(ar[r] + brz_r[r]);
            float zg = fsigm(az[r] + brz_z[r]);
            float ng = ftanh(agi[r] + b_in[r] + rg*(agh[r] + b_hn[r]));
            float hn = (1.0f - zg)*ng + zg*hreg[r];
            hreg[r] = hn;
            hs[wp][c][w*16 + quad*4 + r] = (f16)hn;
            sp += hn * awr[r];
        }
        if (do_stage){
            int s = tid>>4, p = tid&15;
            *(f16x8*)&xs[xp^1][s][p*8] = xstage;
        }
        sp += __shfl_xor(sp, 16);
        sp += __shfl_xor(sp, 32);
        if (lane < 16) scpart[wp][w][lane] = sp;
        __syncthreads();
        float sc = abv;
#pragma unroll
        for (int ww=0; ww<8; ww++) sc += scpart[wp][ww][c];
        float mn = fmaxf(m_, sc);
        float al = __expf(m_ - mn), pp = __expf(sc - mn);
        l_ = l_*al + pp; m_ = mn;
#pragma unroll
        for (int r=0;r<4;r++) aacc[r] = aacc[r]*al + pp*hreg[r];
    }
    // final write parity was hs[1] (t=31) -> reuse hs[1]
    { float inv = 1.0f / l_;
#pragma unroll
      for (int r=0;r<4;r++)
          hs[1][c][w*16 + quad*4 + r] = (f16)(aacc[r]*inv); }
    __syncthreads();
    if (tid < 256){
        int s = tid>>4, p = tid&15;
        *(f16x8*)&out[(size_t)(s0+s)*128 + p*8] = *(const f16x8*)&hs[1][s][p*8];
    }
}

// ---------------------------------------------------------------------------
// Wh = shrt_last @ W  (MFMA).  WT = W^T f16 [128][128]. 64 blocks x 256.
// ---------------------------------------------------------------------------
__global__ __launch_bounds__(256) void wh_mfma(
    const f16* __restrict__ shrt16, const f16* __restrict__ WT,
    float* __restrict__ Wh)
{
    __shared__ __align__(16) float tbuf[32][132];
    const int tid = threadIdx.x, w = tid>>6, lane = tid&63;
    const int c = lane&15, quad = lane>>4;
    const int s0 = blockIdx.x*32;
    f16x8 A[2][4];
#pragma unroll
    for (int mt=0;mt<2;mt++)
#pragma unroll
        for (int kb=0;kb<4;kb++)
            A[mt][kb] = *(const f16x8*)&shrt16[((size_t)(s0+mt*16+c)*32 + 31)*128 + kb*32 + quad*8];
#pragma unroll
    for (int i=0;i<2;i++){
        int jb = w*2 + i;
        f16x8 B[4];
#pragma unroll
        for (int kb=0;kb<4;kb++)
            B[kb] = *(const f16x8*)&WT[(size_t)(jb*16+c)*128 + kb*32 + quad*8];
        floatx4 acc[2] = {{0,0,0,0},{0,0,0,0}};
#pragma unroll
        for (int kb=0;kb<4;kb++){
            acc[0] = MFMA16(A[0][kb], B[kb], acc[0]);
            acc[1] = MFMA16(A[1][kb], B[kb], acc[1]);
        }
#pragma unroll
        for (int mt=0;mt<2;mt++)
#pragma unroll
            for (int r=0;r<4;r++)
                tbuf[mt*16 + quad*4 + r][jb*16 + c] = acc[mt][r];
    }
    __syncthreads();
    for (int i=tid; i<1024; i+=256){
        int s = i>>5, p = i&31;
        *(float4*)&Wh[(size_t)(s0+s)*128 + p*4] = *(const float4*)&tbuf[s][p*4];
    }
}

__global__ __launch_bounds__(256) void elr_kernel(
    const float* __restrict__ Wh, const float* __restrict__ a,
    float* __restrict__ el, float* __restrict__ er, int S)
{
    int wave = threadIdx.x >> 6, lane = threadIdx.x & 63;
    int i = blockIdx.x*4 + wave;
    if (i >= S) return;
    float w0 = Wh[(size_t)i*128+lane], w1 = Wh[(size_t)i*128+64+lane];
    float v1 = w0*a[lane]     + w1*a[64+lane];
    float v2 = w0*a[128+lane] + w1*a[192+lane];
    for (int off=32; off; off>>=1){ v1 += __shfl_down(v1,off); v2 += __shfl_down(v2,off); }
    if (lane==0){ el[i]=v1; er[i]=v2; }
}

__global__ __launch_bounds__(256) void gat_intra_att_kernel(
    const float* __restrict__ Wh, const float* __restrict__ el,
    const float* __restrict__ er, const int* __restrict__ sec,
    f16* __restrict__ outp, int S)
{
    int wave = threadIdx.x>>6, lane = threadIdx.x&63;
    int i = blockIdx.x*4 + wave;
    if (i>=S) return;
    int si = sec[i];
    float eli = el[i];
    float m = NEGBIG;
    for (int jb=0; jb<S; jb+=64){
        int j = jb + lane;
        float e = NEGBIG;
        if (sec[j]==si){ float v = eli + er[j]; e = v>0.f? v : LRELU_A*v; }
        m = fmaxf(m,e);
    }
    for (int off=32; off; off>>=1) m = fmaxf(m, __shfl_xor(m, off));
    float l = 0.f, c0=0.f, c1=0.f;
    for (int j=0;j<S;j++){
        if (sec[j]!=si) continue;
        float v = eli + er[j]; v = v>0.f? v : LRELU_A*v;
        float p = expf(v-m);
        l += p;
        c0 += p*Wh[(size_t)j*128+lane];
        c1 += p*Wh[(size_t)j*128+64+lane];
    }
    c0 /= l; c1 /= l;
    outp[(size_t)i*128+lane]    = (f16)(c0>0.f? c0 : expm1f(c0));
    outp[(size_t)i*128+64+lane] = (f16)(c1>0.f? c1 : expm1f(c1));
}

// ---------------------------------------------------------------------------
// lg: T=1 GRU simplification via MFMA: gi = intra @ Wih^T; lg=(1-z)*n
// ---------------------------------------------------------------------------
__global__ __launch_bounds__(256) void lg_mfma(
    const f16* __restrict__ intra16, const float* __restrict__ Wih,
    const float* __restrict__ bih, const float* __restrict__ bhh,
    f16* __restrict__ lgout)
{
    __shared__ __align__(16) f16 tbuf[32][136];
    const int tid = threadIdx.x, w = tid>>6, lane = tid&63;
    const int c = lane&15, quad = lane>>4;
    const int s0 = blockIdx.x*32;
    f16x8 A[2][4];
#pragma unroll
    for (int mt=0;mt<2;mt++)
#pragma unroll
        for (int kb=0;kb<4;kb++)
            A[mt][kb] = *(const f16x8*)&intra16[(size_t)(s0+mt*16+c)*128 + kb*32 + quad*8];
#pragma unroll
    for (int i=0;i<2;i++){
        int jb = w*2 + i;
        int j = jb*16 + c;
        f16x8 Br[4], Bz[4], Bn[4];
#pragma unroll
        for (int kb=0;kb<4;kb++){
            Br[kb] = load_cvt8(&Wih[(size_t)(j)*128 + kb*32 + quad*8]);
            Bz[kb] = load_cvt8(&Wih[(size_t)(128+j)*128 + kb*32 + quad*8]);
            Bn[kb] = load_cvt8(&Wih[(size_t)(256+j)*128 + kb*32 + quad*8]);
        }
        float b_r = bih[j] + bhh[j];
        float b_z = bih[128+j] + bhh[128+j];
        float b_i = bih[256+j], b_h = bhh[256+j];
        floatx4 ar[2] = {{0,0,0,0},{0,0,0,0}};
        floatx4 az[2] = {{0,0,0,0},{0,0,0,0}};
        floatx4 an[2] = {{0,0,0,0},{0,0,0,0}};
#pragma unroll
        for (int kb=0;kb<4;kb++)
#pragma unroll
            for (int mt=0;mt<2;mt++){
                ar[mt] = MFMA16(A[mt][kb], Br[kb], ar[mt]);
                az[mt] = MFMA16(A[mt][kb], Bz[kb], az[mt]);
                an[mt] = MFMA16(A[mt][kb], Bn[kb], an[mt]);
            }
#pragma unroll
        for (int mt=0;mt<2;mt++)
#pragma unroll
            for (int r=0;r<4;r++){
                float rg = fsigm(ar[mt][r] + b_r);
                float zg = fsigm(az[mt][r] + b_z);
                float ng = ftanh(an[mt][r] + b_i + rg*b_h);
                tbuf[mt*16 + quad*4 + r][j] = (f16)((1.0f - zg)*ng);
            }
    }
    __syncthreads();
    for (int i=tid; i<512; i+=256){
        int s = i>>4, p = i&15;
        *(f16x8*)&lgout[(size_t)(s0+s)*128 + p*8] = *(const f16x8*)&tbuf[s][p*8];
    }
}

__global__ __launch_bounds__(128) void sector_mean_kernel(
    const f16* __restrict__ lg, const int* __restrict__ sec,
    float* __restrict__ secf, int S)
{
    int g = blockIdx.x, j = threadIdx.x;
    float sum=0.f; int cnt=0;
    for (int s=0;s<S;s++){
        if (sec[s]==g){ sum += (float)lg[(size_t)s*128+j]; cnt++; }
    }
    secf[g*128+j] = sum / fmaxf((float)cnt,1.0f);
}

__global__ __launch_bounds__(256) void gat_inter_kernel(
    const float* __restrict__ secf, const int* __restrict__ adj,
    const float* __restrict__ W, const float* __restrict__ a,
    float* __restrict__ outp)
{
    __shared__ __align__(16) float hs[16][132];
    __shared__ __align__(16) float Whs[16][132];
    __shared__ float el[16], er[16];
    __shared__ float att[16][16];
    const int tid=threadIdx.x;
    for (int idx=tid; idx<2048; idx+=256){ int s=idx>>7,j=idx&127; hs[s][j]=secf[idx]; }
    __syncthreads();
#pragma unroll 1
    for (int i=0;i<8;i++){
        int idx=i*256+tid; int o=idx&127, s=idx>>7;
        float a0=0.f,a1=0.f,a2=0.f,a3=0.f;
        for (int j=0;j<128;j+=4){
            a0 += hs[s][j]  *W[(j  )*128+o];
            a1 += hs[s][j+1]*W[(j+1)*128+o];
            a2 += hs[s][j+2]*W[(j+2)*128+o];
            a3 += hs[s][j+3]*W[(j+3)*128+o];
        }
        Whs[s][o]=(a0+a1)+(a2+a3);
    }
    __syncthreads();
    if (tid<32){
        int s=tid&15; int second = tid>>4;
        const float* av = a + (second?128:0);
        float acc=0.f; for(int o=0;o<128;o++) acc += Whs[s][o]*av[o];
        if (second) er[s]=acc; else el[s]=acc;
    }
    __syncthreads();
    if (tid<16){
        int i=tid; float m=NEGBIG; float e[16];
        for(int j=0;j<16;j++){
            float v = el[i]+er[j]; v = v>0.f? v : LRELU_A*v;
            e[j] = (adj[i*16+j]>0)? v : NEGBIG;
            m = fmaxf(m,e[j]);
        }
        float l=0.f;
        for(int j=0;j<16;j++){ float p=expf(e[j]-m); att[i][j]=p; l+=p; }
        for(int j=0;j<16;j++) att[i][j] /= l;
    }
    __syncthreads();
#pragma unroll
    for (int i=0;i<8;i++){
        int idx=i*256+tid; int o=idx&127, s=idx>>7;
        float acc=0.f;
#pragma unroll
        for(int j=0;j<16;j++) acc += att[s][j]*Whs[j][o];
        outp[s*128+o] = acc>0.f? acc : expm1f(acc);
    }
}

// ---------------------------------------------------------------------------
// fused = [lg|la|sec_ps] @ fw + fb, then both heads in-kernel
// ---------------------------------------------------------------------------
__global__ __launch_bounds__(256) void fused_mfma(
    const f16* __restrict__ lg16, const f16* __restrict__ la16,
    const float* __restrict__ seco, const int* __restrict__ sec,
    const f16* __restrict__ fwT,   // [128][384]
    const float* __restrict__ fb, const float* __restrict__ rw,
    const float* __restrict__ rb, const float* __restrict__ mw,
    const float* __restrict__ mb, float* __restrict__ outp)
{
    __shared__ float rpart[4][32], mpart[4][32];
    const int tid = threadIdx.x, w = tid>>6, lane = tid&63;
    const int c = lane&15, quad = lane>>4;
    const int s0 = blockIdx.x*32;
    f16x8 A[2][12];
#pragma unroll
    for (int mt=0;mt<2;mt++){
        int row = s0 + mt*16 + c;
        int g = sec[row];
#pragma unroll
        for (int kb=0;kb<4;kb++){
            A[mt][kb]   = *(const f16x8*)&lg16[(size_t)row*128 + kb*32 + quad*8];
            A[mt][4+kb] = *(const f16x8*)&la16[(size_t)row*128 + kb*32 + quad*8];
            A[mt][8+kb] = load_cvt8(&seco[(size_t)g*128 + kb*32 + quad*8]);
        }
    }
    float rsum[2][4] = {{0,0,0,0},{0,0,0,0}};
    float msum[2][4] = {{0,0,0,0},{0,0,0,0}};
#pragma unroll
    for (int i=0;i<2;i++){
        int jb = w*2 + i;
        int col = jb*16 + c;
        f16x8 B[12];
#pragma unroll
        for (int kb=0;kb<12;kb++)
            B[kb] = *(const f16x8*)&fwT[(size_t)col*384 + kb*32 + quad*8];
        floatx4 acc[2] = {{0,0,0,0},{0,0,0,0}};
#pragma unroll
        for (int kb=0;kb<12;kb++){
            acc[0] = MFMA16(A[0][kb], B[kb], acc[0]);
            acc[1] = MFMA16(A[1][kb], B[kb], acc[1]);
        }
        float fbv = fb[col], rwv = rw[col], mwv = mw[col];
#pragma unroll
        for (int mt=0;mt<2;mt++)
#pragma unroll
            for (int r=0;r<4;r++){
                float fu = acc[mt][r] + fbv;
                rsum[mt][r] += fu*rwv;
                msum[mt][r] += fu*mwv;
            }
    }
#pragma unroll
    for (int mt=0;mt<2;mt++)
#pragma unroll
        for (int r=0;r<4;r++){
#pragma unroll
            for (int off=1; off<16; off<<=1){
                rsum[mt][r] += __shfl_xor(rsum[mt][r], off);
                msum[mt][r] += __shfl_xor(msum[mt][r], off);
            }
            if (c==0){
                rpart[w][mt*16 + quad*4 + r] = rsum[mt][r];
                mpart[w][mt*16 + quad*4 + r] = msum[mt][r];
            }
        }
    __syncthreads();
    if (tid < 32){
        int s = tid;
        float rs = rb[0], ms = mb[0];
#pragma unroll
        for (int ww=0; ww<4; ww++){ rs += rpart[ww][s]; ms += mpart[ww][s]; }
        outp[s0+s] = rs;
        outp[2048 + s0 + s] = sigm(ms);
    }
}

extern "C" void kernel_launch(void* const* d_in, const int* in_sizes, int n_in,
                              void* d_out, int out_size, void* d_ws, size_t ws_size,
                              hipStream_t stream) {
    const float* sf    = (const float*)d_in[0];
    const int*   sec   = (const int*)  d_in[1];
    const int*   adj   = (const int*)  d_in[2];
    const float* g1Wih = (const float*)d_in[3];
    const float* g1Whh = (const float*)d_in[4];
    const float* g1bih = (const float*)d_in[5];
    const float* g1bhh = (const float*)d_in[6];
    const float* a1w   = (const float*)d_in[7];
    const float* a1b   = (const float*)d_in[8];
    const float* giW   = (const float*)d_in[9];
    const float* gia   = (const float*)d_in[10];
    const float* ggWih = (const float*)d_in[11];
    const float* ggbih = (const float*)d_in[13];
    const float* ggbhh = (const float*)d_in[14];
    const float* gaWih = (const float*)d_in[17];
    const float* gaWhh = (const float*)d_in[18];
    const float* gabih = (const float*)d_in[19];
    const float* gabhh = (const float*)d_in[20];
    const float* aaw   = (const float*)d_in[21];
    const float* aab   = (const float*)d_in[22];
    const float* geW   = (const float*)d_in[23];
    const float* gea   = (const float*)d_in[24];
    const float* fw    = (const float*)d_in[25];
    const float* fb    = (const float*)d_in[26];
    const float* rw    = (const float*)d_in[27];
    const float* rb    = (const float*)d_in[28];
    const float* mw    = (const float*)d_in[29];
    const float* mb    = (const float*)d_in[30];

    char* p = (char*)d_ws;
    f16*   shrt16 = (f16*)p;   p += (size_t)65536*128*2;
    float* Wh     = (float*)p; p += (size_t)262144*4;
    float* el     = (float*)p; p += 2048*4;
    float* er     = (float*)p; p += 2048*4;
    f16*   intra16= (f16*)p;   p += (size_t)262144*2;
    f16*   lg16   = (f16*)p;   p += (size_t)262144*2;
    f16*   la16   = (f16*)p;   p += (size_t)262144*2;
    float* secf   = (float*)p; p += 2048*4;
    float* seco   = (float*)p; p += 2048*4;
    f16*   Wcat1  = (f16*)p;   p += (size_t)512*160*2;
    f16*   WcatA  = (f16*)p;   p += (size_t)512*256*2;
    f16*   WT     = (f16*)p;   p += (size_t)16384*2;
    f16*   fwT    = (f16*)p;   p += (size_t)49152*2;

    // weight prep
    build_wcat_kernel<<<160,256,0,stream>>>(g1Wih, g1Whh, Wcat1, 16, 32);
    build_wcat_kernel<<<256,256,0,stream>>>(gaWih, gaWhh, WcatA, 128, 128);
    transpose_cvt<<<64,256,0,stream>>>(giW, WT, 128, 128);
    transpose_cvt<<<192,256,0,stream>>>(fw, fwT, 384, 128);

    // 1. short GRU+attn (65536 windows, T=5)
    gru_short<<<2048,512,0,stream>>>(sf, Wcat1, g1bih, g1bhh, a1w, a1b, shrt16);
    // 2. intra-sector GAT
    wh_mfma<<<64,256,0,stream>>>(shrt16, WT, Wh);
    elr_kernel<<<512,256,0,stream>>>(Wh, gia, el, er, 2048);
    gat_intra_att_kernel<<<512,256,0,stream>>>(Wh, el, er, sec, intra16, 2048);
    // 3. lg (T=1 simplification)
    lg_mfma<<<64,256,0,stream>>>(intra16, ggWih, ggbih, ggbhh, lg16);
    // 4. la GRU+attn (2048 seqs, T=32)
    gru_la<<<128,512,0,stream>>>(shrt16, WcatA, gabih, gabhh, aaw, aab, la16);
    // 5. sector means
    sector_mean_kernel<<<16,128,0,stream>>>(lg16, sec, secf, 2048);
    // 6. inter-sector GAT
    gat_inter_kernel<<<1,256,0,stream>>>(secf, adj, geW, gea, seco);
    // 7. fusion + heads
    fused_mfma<<<64,256,0,stream>>>(lg16, la16, seco, sec, fwT, fb, rw, rb, mw, mb, (float*)d_out);
}

// Round 4
// 409.112 us; speedup vs baseline: 9.7081x; 1.5199x over previous
//
#include <hip/hip_runtime.h>
#include <math.h>

#define LRELU_A 0.2f
#define NEGBIG (-9.0e15f)

typedef _Float16 f16;
typedef _Float16 f16x8 __attribute__((ext_vector_type(8)));
typedef _Float16 f16x4 __attribute__((ext_vector_type(4)));
typedef float floatx4 __attribute__((ext_vector_type(4)));

__device__ __forceinline__ float sigm(float x){ return 1.0f/(1.0f+expf(-x)); }
__device__ __forceinline__ float fsigm(float x){ return 1.0f/(1.0f+__expf(-x)); }
__device__ __forceinline__ float ftanh(float x){
    float ax = fabsf(x);
    float e = __expf(2.0f*ax);
    float t = 1.0f - 2.0f/(e+1.0f);
    return copysignf(t,x);
}
__device__ __forceinline__ f16x8 load_cvt8(const float* __restrict__ p){
    float4 a = *(const float4*)p; float4 b = *(const float4*)(p+4);
    f16x8 r; r[0]=(f16)a.x; r[1]=(f16)a.y; r[2]=(f16)a.z; r[3]=(f16)a.w;
    r[4]=(f16)b.x; r[5]=(f16)b.y; r[6]=(f16)b.z; r[7]=(f16)b.w;
    return r;
}
#define MFMA16(A,B,C) __builtin_amdgcn_mfma_f32_16x16x32_f16((A),(B),(C),0,0,0)

// ---------------------------------------------------------------------------
// Wcat[512][KTOT], KTOT = INFPAD+128. rows 0..255: [Wih_rz | Whh_rz];
// 256..383: [Wih_n | 0]; 384..511: [0 | Whh_n]
// ---------------------------------------------------------------------------
__global__ __launch_bounds__(256) void build_wcat_kernel(
    const float* __restrict__ Wih, const float* __restrict__ Whh,
    f16* __restrict__ Wcat, int INF, int INFPAD)
{
    int KTOT = INFPAD + 128;
    int total = 512*KTOT;
    for (int idx = blockIdx.x*256 + threadIdx.x; idx < total; idx += gridDim.x*256){
        int r = idx / KTOT, k = idx - r*KTOT;
        float v = 0.0f;
        if (r < 256){
            if (k < INFPAD){ if (k < INF) v = Wih[r*INF + k]; }
            else v = Whh[r*128 + (k - INFPAD)];
        } else if (r < 384){
            if (k < INF) v = Wih[r*INF + k];
        } else {
            if (k >= INFPAD) v = Whh[(r-128)*128 + (k - INFPAD)];
        }
        Wcat[idx] = (f16)v;
    }
}

// out[c*R + r] = (f16) in[r*C + c]
__global__ __launch_bounds__(256) void transpose_cvt(
    const float* __restrict__ in, f16* __restrict__ out, int R, int C)
{
    for (int idx = blockIdx.x*256+threadIdx.x; idx < R*C; idx += gridDim.x*256){
        int r = idx / C, c = idx - r*C;
        out[(size_t)c*R + r] = (f16)in[idx];
    }
}

// ---------------------------------------------------------------------------
// Sector bucketing: member lists, counts, exclusive-prefix bases. One block.
// ---------------------------------------------------------------------------
__global__ __launch_bounds__(256) void bucket_kernel(
    const int* __restrict__ sec, int* __restrict__ mem,
    int* __restrict__ cnt, int* __restrict__ base, int S)
{
    __shared__ int cs[16];
    const int tid = threadIdx.x;
    if (tid < 16) cs[tid] = 0;
    __syncthreads();
    for (int s = tid; s < S; s += 256){
        int g = sec[s];
        int p = atomicAdd(&cs[g], 1);
        mem[g*2048 + p] = s;
    }
    __syncthreads();
    if (tid == 0){
        int b = 0;
        for (int g=0; g<16; g++){ cnt[g] = cs[g]; base[g] = b; b += cs[g]; }
    }
}

// gather Wh rows + er into sector-sorted contiguous arrays (f16 / f32)
__global__ __launch_bounds__(64) void gather_sorted_kernel(
    const float* __restrict__ Wh, const float* __restrict__ er,
    const int* __restrict__ mem, const int* __restrict__ cnt,
    const int* __restrict__ base,
    f16* __restrict__ Whs, float* __restrict__ ers)
{
    int p = blockIdx.x, lane = threadIdx.x;
    int g = 0;
#pragma unroll
    for (int t=0; t<16; t++) if (p >= base[t] + cnt[t]) g = t+1;
    if (g > 15) return;
    int j = mem[g*2048 + (p - base[g])];
    Whs[(size_t)p*128 + lane]      = (f16)Wh[(size_t)j*128 + lane];
    Whs[(size_t)p*128 + 64 + lane] = (f16)Wh[(size_t)j*128 + 64 + lane];
    if (lane == 0) ers[p] = er[j];
}

// ---------------------------------------------------------------------------
// Short GRU+attn, gate-partitioned. M=32 seqs/block, 8 waves, T=5.
// ---------------------------------------------------------------------------
__global__ __launch_bounds__(512,2) void gru_short(
    const float* __restrict__ x, const f16* __restrict__ Wcat,
    const float* __restrict__ bih, const float* __restrict__ bhh,
    const float* __restrict__ aw, const float* __restrict__ ab,
    f16* __restrict__ out)
{
    __shared__ __align__(16) f16 xs[5][32][40];
    __shared__ __align__(16) f16 hs[2][32][136];
    __shared__ float scpart[2][8][32];
    const int tid = threadIdx.x, w = tid>>6, lane = tid&63;
    const int c = lane&15, quad = lane>>4;
    const int s0 = blockIdx.x*32;

    { f16x4 z4 = {0,0,0,0};
      f16x4* zx = (f16x4*)&xs[0][0][0];
      for (int i=tid; i<1600; i+=512) zx[i] = z4;
      f16x4* zh = (f16x4*)&hs[1][0][0];
      for (int i=tid; i<1088; i+=512) zh[i] = z4; }
    for (int i=tid; i<640; i+=512){
        int s = i/20, q = i - 20*s;
        float4 v = *(const float4*)&x[(size_t)(s0+s)*80 + q*4];
        int t = (q*4)>>4, f = (q*4)&15;
        f16x4 h4; h4[0]=(f16)v.x; h4[1]=(f16)v.y; h4[2]=(f16)v.z; h4[3]=(f16)v.w;
        *(f16x4*)&xs[t][s][f] = h4;
    }
    const int jrow = w*16 + c;
    f16x8 Ar[5], Az[5], Agi, Agh[4];
#pragma unroll
    for (int kb=0;kb<5;kb++){
        Ar[kb] = *(const f16x8*)&Wcat[(size_t)(jrow)*160 + kb*32 + quad*8];
        Az[kb] = *(const f16x8*)&Wcat[(size_t)(128+jrow)*160 + kb*32 + quad*8];
    }
    Agi = *(const f16x8*)&Wcat[(size_t)(256+jrow)*160 + quad*8];
#pragma unroll
    for (int i=0;i<4;i++)
        Agh[i] = *(const f16x8*)&Wcat[(size_t)(384+jrow)*160 + 32 + i*32 + quad*8];

    float brz_r[4], brz_z[4], b_in[4], b_hn[4], awr[4];
#pragma unroll
    for (int r=0;r<4;r++){
        int j = w*16 + quad*4 + r;
        brz_r[r] = bih[j] + bhh[j];
        brz_z[r] = bih[128+j] + bhh[128+j];
        b_in[r] = bih[256+j]; b_hn[r] = bhh[256+j];
        awr[r] = aw[j];
    }
    const float abv = ab[0];
    float hreg[2][4], aacc[2][4], m_[2], l_[2];
#pragma unroll
    for (int st=0; st<2; st++){
        m_[st] = -INFINITY; l_[st] = 0.0f;
#pragma unroll
        for (int r=0;r<4;r++){ hreg[st][r]=0.0f; aacc[st][r]=0.0f; }
    }
    __syncthreads();

#pragma unroll 1
    for (int t=0; t<5; ++t){
        const int rp = (t&1)^1, wp = t&1;
        f16x8 Bx[2], Bh[2][4];
#pragma unroll
        for (int st=0; st<2; st++){
            Bx[st] = *(const f16x8*)&xs[t][st*16+c][quad*8];
#pragma unroll
            for (int i=0;i<4;i++)
                Bh[st][i] = *(const f16x8*)&hs[rp][st*16+c][i*32+quad*8];
        }
        float sp[2];
#pragma unroll
        for (int st=0; st<2; st++){
            floatx4 ar = {0,0,0,0}, az = {0,0,0,0}, agi = {0,0,0,0}, agh = {0,0,0,0};
            ar = MFMA16(Ar[0], Bx[st], ar);
            az = MFMA16(Az[0], Bx[st], az);
            agi = MFMA16(Agi, Bx[st], agi);
#pragma unroll
            for (int i=0;i<4;i++){
                ar = MFMA16(Ar[1+i], Bh[st][i], ar);
                az = MFMA16(Az[1+i], Bh[st][i], az);
                agh = MFMA16(Agh[i], Bh[st][i], agh);
            }
            sp[st] = 0.0f;
#pragma unroll
            for (int r=0;r<4;r++){
                float rg = fsigm(ar[r] + brz_r[r]);
                float zg = fsigm(az[r] + brz_z[r]);
                float ng = ftanh(agi[r] + b_in[r] + rg*(agh[r] + b_hn[r]));
                float hn = (1.0f - zg)*ng + zg*hreg[st][r];
                hreg[st][r] = hn;
                hs[wp][st*16 + c][w*16 + quad*4 + r] = (f16)hn;
                sp[st] += hn * awr[r];
            }
        }
#pragma unroll
        for (int st=0; st<2; st++){
            sp[st] += __shfl_xor(sp[st], 16);
            sp[st] += __shfl_xor(sp[st], 32);
        }
        if (lane < 16){ scpart[wp][w][lane] = sp[0]; scpart[wp][w][16+lane] = sp[1]; }
        __syncthreads();
#pragma unroll
        for (int st=0; st<2; st++){
            float sc = abv;
#pragma unroll
            for (int ww=0; ww<8; ww++) sc += scpart[wp][ww][st*16+c];
            float mo = m_[st], mn = fmaxf(mo, sc);
            float al = __expf(mo - mn), pp = __expf(sc - mn);
            l_[st] = l_[st]*al + pp; m_[st] = mn;
#pragma unroll
            for (int r=0;r<4;r++) aacc[st][r] = aacc[st][r]*al + pp*hreg[st][r];
        }
    }
#pragma unroll
    for (int st=0; st<2; st++){
        float inv = 1.0f / l_[st];
#pragma unroll
        for (int r=0;r<4;r++)
            hs[0][st*16 + c][w*16 + quad*4 + r] = (f16)(aacc[st][r]*inv);
    }
    __syncthreads();
    { int s = tid>>4, p = tid&15;
      *(f16x8*)&out[(size_t)(s0+s)*128 + p*8] = *(const f16x8*)&hs[0][s][p*8]; }
}

// ---------------------------------------------------------------------------
// la GRU+attn, gate-partitioned. M=16 seqs/block, 8 waves, T=32.
// ---------------------------------------------------------------------------
__global__ __launch_bounds__(512,2) void gru_la(
    const f16* __restrict__ xseq, const f16* __restrict__ Wcat,
    const float* __restrict__ bih, const float* __restrict__ bhh,
    const float* __restrict__ aw, const float* __restrict__ ab,
    f16* __restrict__ out)
{
    __shared__ __align__(16) f16 xs[2][16][136];
    __shared__ __align__(16) f16 hs[2][16][136];
    __shared__ float scpart[2][8][16];
    const int tid = threadIdx.x, w = tid>>6, lane = tid&63;
    const int c = lane&15, quad = lane>>4;
    const int s0 = blockIdx.x*16;

    { f16x4 z4 = {0,0,0,0};
      f16x4* zh = (f16x4*)&hs[1][0][0];
      for (int i=tid; i<544; i+=512) zh[i] = z4; }
    if (tid < 256){
        int s = tid>>4, p = tid&15;
        *(f16x8*)&xs[0][s][p*8] = *(const f16x8*)&xseq[((size_t)(s0+s)*32 + 0)*128 + p*8];
    }
    const int jrow = w*16 + c;
    f16x8 Ar[8], Az[8], Agi[4], Agh[4];
#pragma unroll
    for (int kb=0;kb<8;kb++){
        Ar[kb] = *(const f16x8*)&Wcat[(size_t)(jrow)*256 + kb*32 + quad*8];
        Az[kb] = *(const f16x8*)&Wcat[(size_t)(128+jrow)*256 + kb*32 + quad*8];
    }
#pragma unroll
    for (int i=0;i<4;i++){
        Agi[i] = *(const f16x8*)&Wcat[(size_t)(256+jrow)*256 + i*32 + quad*8];
        Agh[i] = *(const f16x8*)&Wcat[(size_t)(384+jrow)*256 + 128 + i*32 + quad*8];
    }
    float brz_r[4], brz_z[4], b_in[4], b_hn[4], awr[4];
#pragma unroll
    for (int r=0;r<4;r++){
        int j = w*16 + quad*4 + r;
        brz_r[r] = bih[j] + bhh[j];
        brz_z[r] = bih[128+j] + bhh[128+j];
        b_in[r] = bih[256+j]; b_hn[r] = bhh[256+j];
        awr[r] = aw[j];
    }
    const float abv = ab[0];
    float hreg[4] = {0,0,0,0}, aacc[4] = {0,0,0,0};
    float m_ = -INFINITY, l_ = 0.0f;
    __syncthreads();

#pragma unroll 1
    for (int t=0; t<32; ++t){
        const int rp = (t&1)^1, wp = t&1, xp = t&1;
        f16x8 Bx[4], Bh[4];
#pragma unroll
        for (int i=0;i<4;i++){
            Bx[i] = *(const f16x8*)&xs[xp][c][i*32+quad*8];
            Bh[i] = *(const f16x8*)&hs[rp][c][i*32+quad*8];
        }
        f16x8 xstage;
        const bool do_stage = (t < 31) && (tid < 256);
        if (do_stage){
            int s = tid>>4, p = tid&15;
            xstage = *(const f16x8*)&xseq[((size_t)(s0+s)*32 + t+1)*128 + p*8];
        }
        floatx4 ar = {0,0,0,0}, az = {0,0,0,0}, agi = {0,0,0,0}, agh = {0,0,0,0};
#pragma unroll
        for (int i=0;i<4;i++){
            ar = MFMA16(Ar[i], Bx[i], ar);
            az = MFMA16(Az[i], Bx[i], az);
            agi = MFMA16(Agi[i], Bx[i], agi);
        }
#pragma unroll
        for (int i=0;i<4;i++){
            ar = MFMA16(Ar[4+i], Bh[i], ar);
            az = MFMA16(Az[4+i], Bh[i], az);
            agh = MFMA16(Agh[i], Bh[i], agh);
        }
        float sp = 0.0f;
#pragma unroll
        for (int r=0;r<4;r++){
            float rg = fsigm(ar[r] + brz_r[r]);
            float zg = fsigm(az[r] + brz_z[r]);
            float ng = ftanh(agi[r] + b_in[r] + rg*(agh[r] + b_hn[r]));
            float hn = (1.0f - zg)*ng + zg*hreg[r];
            hreg[r] = hn;
            hs[wp][c][w*16 + quad*4 + r] = (f16)hn;
            sp += hn * awr[r];
        }
        if (do_stage){
            int s = tid>>4, p = tid&15;
            *(f16x8*)&xs[xp^1][s][p*8] = xstage;
        }
        sp += __shfl_xor(sp, 16);
        sp += __shfl_xor(sp, 32);
        if (lane < 16) scpart[wp][w][lane] = sp;
        __syncthreads();
        float sc = abv;
#pragma unroll
        for (int ww=0; ww<8; ww++) sc += scpart[wp][ww][c];
        float mn = fmaxf(m_, sc);
        float al = __expf(m_ - mn), pp = __expf(sc - mn);
        l_ = l_*al + pp; m_ = mn;
#pragma unroll
        for (int r=0;r<4;r++) aacc[r] = aacc[r]*al + pp*hreg[r];
    }
    { float inv = 1.0f / l_;
#pragma unroll
      for (int r=0;r<4;r++)
          hs[1][c][w*16 + quad*4 + r] = (f16)(aacc[r]*inv); }
    __syncthreads();
    if (tid < 256){
        int s = tid>>4, p = tid&15;
        *(f16x8*)&out[(size_t)(s0+s)*128 + p*8] = *(const f16x8*)&hs[1][s][p*8];
    }
}

// ---------------------------------------------------------------------------
// Wh = shrt_last @ W  (MFMA)
// ---------------------------------------------------------------------------
__global__ __launch_bounds__(256) void wh_mfma(
    const f16* __restrict__ shrt16, const f16* __restrict__ WT,
    float* __restrict__ Wh)
{
    __shared__ __align__(16) float tbuf[32][132];
    const int tid = threadIdx.x, w = tid>>6, lane = tid&63;
    const int c = lane&15, quad = lane>>4;
    const int s0 = blockIdx.x*32;
    f16x8 A[2][4];
#pragma unroll
    for (int mt=0;mt<2;mt++)
#pragma unroll
        for (int kb=0;kb<4;kb++)
            A[mt][kb] = *(const f16x8*)&shrt16[((size_t)(s0+mt*16+c)*32 + 31)*128 + kb*32 + quad*8];
#pragma unroll
    for (int i=0;i<2;i++){
        int jb = w*2 + i;
        f16x8 B[4];
#pragma unroll
        for (int kb=0;kb<4;kb++)
            B[kb] = *(const f16x8*)&WT[(size_t)(jb*16+c)*128 + kb*32 + quad*8];
        floatx4 acc[2] = {{0,0,0,0},{0,0,0,0}};
#pragma unroll
        for (int kb=0;kb<4;kb++){
            acc[0] = MFMA16(A[0][kb], B[kb], acc[0]);
            acc[1] = MFMA16(A[1][kb], B[kb], acc[1]);
        }
#pragma unroll
        for (int mt=0;mt<2;mt++)
#pragma unroll
            for (int r=0;r<4;r++)
                tbuf[mt*16 + quad*4 + r][jb*16 + c] = acc[mt][r];
    }
    __syncthreads();
    for (int i=tid; i<1024; i+=256){
        int s = i>>5, p = i&31;
        *(float4*)&Wh[(size_t)(s0+s)*128 + p*4] = *(const float4*)&tbuf[s][p*4];
    }
}

__global__ __launch_bounds__(256) void elr_kernel(
    const float* __restrict__ Wh, const float* __restrict__ a,
    float* __restrict__ el, float* __restrict__ er, int S)
{
    int wave = threadIdx.x >> 6, lane = threadIdx.x & 63;
    int i = blockIdx.x*4 + wave;
    if (i >= S) return;
    float w0 = Wh[(size_t)i*128+lane], w1 = Wh[(size_t)i*128+64+lane];
    float v1 = w0*a[lane]     + w1*a[64+lane];
    float v2 = w0*a[128+lane] + w1*a[192+lane];
    for (int off=32; off; off>>=1){ v1 += __shfl_down(v1,off); v2 += __shfl_down(v2,off); }
    if (lane==0){ el[i]=v1; er[i]=v2; }
}

// ---------------------------------------------------------------------------
// GAT intra: member-list version. One wave per row; streams sorted f16 Wh.
// ---------------------------------------------------------------------------
__global__ __launch_bounds__(256) void gat_intra_mem_kernel(
    const f16* __restrict__ Whs, const float* __restrict__ ers,
    const float* __restrict__ el, const int* __restrict__ sec,
    const int* __restrict__ cnt, const int* __restrict__ base,
    f16* __restrict__ outp, int S)
{
    int wave = threadIdx.x>>6, lane = threadIdx.x&63;
    int i = blockIdx.x*4 + wave;
    if (i>=S) return;
    int g = sec[i];
    int n = cnt[g], b = base[g];
    float eli = el[i];
    float m = -INFINITY;
    for (int jj=lane; jj<n; jj+=64){
        float v = eli + ers[b+jj]; v = v>0.f? v : LRELU_A*v;
        m = fmaxf(m, v);
    }
#pragma unroll
    for (int off=32; off; off>>=1) m = fmaxf(m, __shfl_xor(m, off));
    float l = 0.f, c0=0.f, c1=0.f;
#pragma unroll 4
    for (int jj=0; jj<n; jj++){
        float v = eli + ers[b+jj]; v = v>0.f? v : LRELU_A*v;
        float p = __expf(v-m);
        l += p;
        c0 += p*(float)Whs[(size_t)(b+jj)*128 + lane];
        c1 += p*(float)Whs[(size_t)(b+jj)*128 + 64 + lane];
    }
    c0 /= l; c1 /= l;
    outp[(size_t)i*128+lane]    = (f16)(c0>0.f? c0 : expm1f(c0));
    outp[(size_t)i*128+64+lane] = (f16)(c1>0.f? c1 : expm1f(c1));
}

// ---------------------------------------------------------------------------
// lg: T=1 GRU simplification via MFMA
// ---------------------------------------------------------------------------
__global__ __launch_bounds__(256) void lg_mfma(
    const f16* __restrict__ intra16, const float* __restrict__ Wih,
    const float* __restrict__ bih, const float* __restrict__ bhh,
    f16* __restrict__ lgout)
{
    __shared__ __align__(16) f16 tbuf[32][136];
    const int tid = threadIdx.x, w = tid>>6, lane = tid&63;
    const int c = lane&15, quad = lane>>4;
    const int s0 = blockIdx.x*32;
    f16x8 A[2][4];
#pragma unroll
    for (int mt=0;mt<2;mt++)
#pragma unroll
        for (int kb=0;kb<4;kb++)
            A[mt][kb] = *(const f16x8*)&intra16[(size_t)(s0+mt*16+c)*128 + kb*32 + quad*8];
#pragma unroll
    for (int i=0;i<2;i++){
        int jb = w*2 + i;
        int j = jb*16 + c;
        f16x8 Br[4], Bz[4], Bn[4];
#pragma unroll
        for (int kb=0;kb<4;kb++){
            Br[kb] = load_cvt8(&Wih[(size_t)(j)*128 + kb*32 + quad*8]);
            Bz[kb] = load_cvt8(&Wih[(size_t)(128+j)*128 + kb*32 + quad*8]);
            Bn[kb] = load_cvt8(&Wih[(size_t)(256+j)*128 + kb*32 + quad*8]);
        }
        float b_r = bih[j] + bhh[j];
        float b_z = bih[128+j] + bhh[128+j];
        float b_i = bih[256+j], b_h = bhh[256+j];
        floatx4 ar[2] = {{0,0,0,0},{0,0,0,0}};
        floatx4 az[2] = {{0,0,0,0},{0,0,0,0}};
        floatx4 an[2] = {{0,0,0,0},{0,0,0,0}};
#pragma unroll
        for (int kb=0;kb<4;kb++)
#pragma unroll
            for (int mt=0;mt<2;mt++){
                ar[mt] = MFMA16(A[mt][kb], Br[kb], ar[mt]);
                az[mt] = MFMA16(A[mt][kb], Bz[kb], az[mt]);
                an[mt] = MFMA16(A[mt][kb], Bn[kb], an[mt]);
            }
#pragma unroll
        for (int mt=0;mt<2;mt++)
#pragma unroll
            for (int r=0;r<4;r++){
                float rg = fsigm(ar[mt][r] + b_r);
                float zg = fsigm(az[mt][r] + b_z);
                float ng = ftanh(an[mt][r] + b_i + rg*b_h);
                tbuf[mt*16 + quad*4 + r][j] = (f16)((1.0f - zg)*ng);
            }
    }
    __syncthreads();
    for (int i=tid; i<512; i+=256){
        int s = i>>4, p = i&15;
        *(f16x8*)&lgout[(size_t)(s0+s)*128 + p*8] = *(const f16x8*)&tbuf[s][p*8];
    }
}

// sector means via member lists: block g, thread j
__global__ __launch_bounds__(128) void sector_mean_mem_kernel(
    const f16* __restrict__ lg, const int* __restrict__ mem,
    const int* __restrict__ cnt, float* __restrict__ secf)
{
    int g = blockIdx.x, j = threadIdx.x;
    int n = cnt[g];
    const int* ml = mem + g*2048;
    float sum=0.f;
    for (int k=0;k<n;k++) sum += (float)lg[(size_t)ml[k]*128 + j];
    secf[g*128+j] = sum / fmaxf((float)n,1.0f);
}

__global__ __launch_bounds__(256) void gat_inter_kernel(
    const float* __restrict__ secf, const int* __restrict__ adj,
    const float* __restrict__ W, const float* __restrict__ a,
    float* __restrict__ outp)
{
    __shared__ __align__(16) float hs[16][132];
    __shared__ __align__(16) float Whs[16][132];
    __shared__ float el[16], er[16];
    __shared__ float att[16][16];
    const int tid=threadIdx.x;
    for (int idx=tid; idx<2048; idx+=256){ int s=idx>>7,j=idx&127; hs[s][j]=secf[idx]; }
    __syncthreads();
#pragma unroll 1
    for (int i=0;i<8;i++){
        int idx=i*256+tid; int o=idx&127, s=idx>>7;
        float a0=0.f,a1=0.f,a2=0.f,a3=0.f;
        for (int j=0;j<128;j+=4){
            a0 += hs[s][j]  *W[(j  )*128+o];
            a1 += hs[s][j+1]*W[(j+1)*128+o];
            a2 += hs[s][j+2]*W[(j+2)*128+o];
            a3 += hs[s][j+3]*W[(j+3)*128+o];
        }
        Whs[s][o]=(a0+a1)+(a2+a3);
    }
    __syncthreads();
    if (tid<32){
        int s=tid&15; int second = tid>>4;
        const float* av = a + (second?128:0);
        float acc=0.f; for(int o=0;o<128;o++) acc += Whs[s][o]*av[o];
        if (second) er[s]=acc; else el[s]=acc;
    }
    __syncthreads();
    if (tid<16){
        int i=tid; float m=NEGBIG; float e[16];
        for(int j=0;j<16;j++){
            float v = el[i]+er[j]; v = v>0.f? v : LRELU_A*v;
            e[j] = (adj[i*16+j]>0)? v : NEGBIG;
            m = fmaxf(m,e[j]);
        }
        float l=0.f;
        for(int j=0;j<16;j++){ float p=expf(e[j]-m); att[i][j]=p; l+=p; }
        for(int j=0;j<16;j++) att[i][j] /= l;
    }
    __syncthreads();
#pragma unroll
    for (int i=0;i<8;i++){
        int idx=i*256+tid; int o=idx&127, s=idx>>7;
        float acc=0.f;
#pragma unroll
        for(int j=0;j<16;j++) acc += att[s][j]*Whs[j][o];
        outp[s*128+o] = acc>0.f? acc : expm1f(acc);
    }
}

// ---------------------------------------------------------------------------
// fused = [lg|la|sec_ps] @ fw + fb, then both heads in-kernel
// ---------------------------------------------------------------------------
__global__ __launch_bounds__(256) void fused_mfma(
    const f16* __restrict__ lg16, const f16* __restrict__ la16,
    const float* __restrict__ seco, const int* __restrict__ sec,
    const f16* __restrict__ fwT,
    const float* __restrict__ fb, const float* __restrict__ rw,
    const float* __restrict__ rb, const float* __restrict__ mw,
    const float* __restrict__ mb, float* __restrict__ outp)
{
    __shared__ float rpart[4][32], mpart[4][32];
    const int tid = threadIdx.x, w = tid>>6, lane = tid&63;
    const int c = lane&15, quad = lane>>4;
    const int s0 = blockIdx.x*32;
    f16x8 A[2][12];
#pragma unroll
    for (int mt=0;mt<2;mt++){
        int row = s0 + mt*16 + c;
        int g = sec[row];
#pragma unroll
        for (int kb=0;kb<4;kb++){
            A[mt][kb]   = *(const f16x8*)&lg16[(size_t)row*128 + kb*32 + quad*8];
            A[mt][4+kb] = *(const f16x8*)&la16[(size_t)row*128 + kb*32 + quad*8];
            A[mt][8+kb] = load_cvt8(&seco[(size_t)g*128 + kb*32 + quad*8]);
        }
    }
    float rsum[2][4] = {{0,0,0,0},{0,0,0,0}};
    float msum[2][4] = {{0,0,0,0},{0,0,0,0}};
#pragma unroll
    for (int i=0;i<2;i++){
        int jb = w*2 + i;
        int col = jb*16 + c;
        f16x8 B[12];
#pragma unroll
        for (int kb=0;kb<12;kb++)
            B[kb] = *(const f16x8*)&fwT[(size_t)col*384 + kb*32 + quad*8];
        floatx4 acc[2] = {{0,0,0,0},{0,0,0,0}};
#pragma unroll
        for (int kb=0;kb<12;kb++){
            acc[0] = MFMA16(A[0][kb], B[kb], acc[0]);
            acc[1] = MFMA16(A[1][kb], B[kb], acc[1]);
        }
        float fbv = fb[col], rwv = rw[col], mwv = mw[col];
#pragma unroll
        for (int mt=0;mt<2;mt++)
#pragma unroll
            for (int r=0;r<4;r++){
                float fu = acc[mt][r] + fbv;
                rsum[mt][r] += fu*rwv;
                msum[mt][r] += fu*mwv;
            }
    }
#pragma unroll
    for (int mt=0;mt<2;mt++)
#pragma unroll
        for (int r=0;r<4;r++){
#pragma unroll
            for (int off=1; off<16; off<<=1){
                rsum[mt][r] += __shfl_xor(rsum[mt][r], off);
                msum[mt][r] += __shfl_xor(msum[mt][r], off);
            }
            if (c==0){
                rpart[w][mt*16 + quad*4 + r] = rsum[mt][r];
                mpart[w][mt*16 + quad*4 + r] = msum[mt][r];
            }
        }
    __syncthreads();
    if (tid < 32){
        int s = tid;
        float rs = rb[0], ms = mb[0];
#pragma unroll
        for (int ww=0; ww<4; ww++){ rs += rpart[ww][s]; ms += mpart[ww][s]; }
        outp[s0+s] = rs;
        outp[2048 + s0 + s] = sigm(ms);
    }
}

extern "C" void kernel_launch(void* const* d_in, const int* in_sizes, int n_in,
                              void* d_out, int out_size, void* d_ws, size_t ws_size,
                              hipStream_t stream) {
    const float* sf    = (const float*)d_in[0];
    const int*   sec   = (const int*)  d_in[1];
    const int*   adj   = (const int*)  d_in[2];
    const float* g1Wih = (const float*)d_in[3];
    const float* g1Whh = (const float*)d_in[4];
    const float* g1bih = (const float*)d_in[5];
    const float* g1bhh = (const float*)d_in[6];
    const float* a1w   = (const float*)d_in[7];
    const float* a1b   = (const float*)d_in[8];
    const float* giW   = (const float*)d_in[9];
    const float* gia   = (const float*)d_in[10];
    const float* ggWih = (const float*)d_in[11];
    const float* ggbih = (const float*)d_in[13];
    const float* ggbhh = (const float*)d_in[14];
    const float* gaWih = (const float*)d_in[17];
    const float* gaWhh = (const float*)d_in[18];
    const float* gabih = (const float*)d_in[19];
    const float* gabhh = (const float*)d_in[20];
    const float* aaw   = (const float*)d_in[21];
    const float* aab   = (const float*)d_in[22];
    const float* geW   = (const float*)d_in[23];
    const float* gea   = (const float*)d_in[24];
    const float* fw    = (const float*)d_in[25];
    const float* fb    = (const float*)d_in[26];
    const float* rw    = (const float*)d_in[27];
    const float* rb    = (const float*)d_in[28];
    const float* mw    = (const float*)d_in[29];
    const float* mb    = (const float*)d_in[30];

    char* p = (char*)d_ws;
    f16*   shrt16 = (f16*)p;   p += (size_t)65536*128*2;
    float* Wh     = (float*)p; p += (size_t)262144*4;
    float* el     = (float*)p; p += 2048*4;
    float* er     = (float*)p; p += 2048*4;
    f16*   intra16= (f16*)p;   p += (size_t)262144*2;
    f16*   lg16   = (f16*)p;   p += (size_t)262144*2;
    f16*   la16   = (f16*)p;   p += (size_t)262144*2;
    float* secf   = (float*)p; p += 2048*4;
    float* seco   = (float*)p; p += 2048*4;
    f16*   Wcat1  = (f16*)p;   p += (size_t)512*160*2;
    f16*   WcatA  = (f16*)p;   p += (size_t)512*256*2;
    f16*   WT     = (f16*)p;   p += (size_t)16384*2;
    f16*   fwT    = (f16*)p;   p += (size_t)49152*2;
    int*   mem    = (int*)p;   p += (size_t)16*2048*4;
    int*   cnt    = (int*)p;   p += 16*4;
    int*   basep  = (int*)p;   p += 16*4;
    f16*   Whs    = (f16*)p;   p += (size_t)2048*128*2;
    float* ers    = (float*)p; p += 2048*4;

    // weight prep + bucketing (no deps on heavy kernels)
    build_wcat_kernel<<<160,256,0,stream>>>(g1Wih, g1Whh, Wcat1, 16, 32);
    build_wcat_kernel<<<256,256,0,stream>>>(gaWih, gaWhh, WcatA, 128, 128);
    transpose_cvt<<<64,256,0,stream>>>(giW, WT, 128, 128);
    transpose_cvt<<<192,256,0,stream>>>(fw, fwT, 384, 128);
    bucket_kernel<<<1,256,0,stream>>>(sec, mem, cnt, basep, 2048);

    // 1. short GRU+attn (65536 windows, T=5)
    gru_short<<<2048,512,0,stream>>>(sf, Wcat1, g1bih, g1bhh, a1w, a1b, shrt16);
    // 2. intra-sector GAT
    wh_mfma<<<64,256,0,stream>>>(shrt16, WT, Wh);
    elr_kernel<<<512,256,0,stream>>>(Wh, gia, el, er, 2048);
    gather_sorted_kernel<<<2048,64,0,stream>>>(Wh, er, mem, cnt, basep, Whs, ers);
    gat_intra_mem_kernel<<<512,256,0,stream>>>(Whs, ers, el, sec, cnt, basep, intra16, 2048);
    // 3. lg (T=1 simplification)
    lg_mfma<<<64,256,0,stream>>>(intra16, ggWih, ggbih, ggbhh, lg16);
    // 4. la GRU+attn (2048 seqs, T=32)
    gru_la<<<128,512,0,stream>>>(shrt16, WcatA, gabih, gabhh, aaw, aab, la16);
    // 5. sector means (member lists)
    sector_mean_mem_kernel<<<16,128,0,stream>>>(lg16, mem, cnt, secf);
    // 6. inter-sector GAT
    gat_inter_kernel<<<1,256,0,stream>>>(secf, adj, geW, gea, seco);
    // 7. fusion + heads
    fused_mfma<<<64,256,0,stream>>>(lg16, la16, seco, sec, fwT, fb, rw, rb, mw, mb, (float*)d_out);
}